// Round 6
// baseline (367.608 us; speedup 1.0000x reference)
//
#include <hip/hip_runtime.h>
#include <hip/hip_bf16.h>
#include <stdint.h>

static constexpr int NN = 50000;   // nodes
static constexpr int NE = 400000;  // edges
static constexpr int NB = (NN + 1023) / 1024;  // 49 scan blocks

typedef __attribute__((ext_vector_type(8))) short bf16x8;
typedef __attribute__((ext_vector_type(4))) float f32x4;

__device__ inline ushort f2bf(float f) {
    __hip_bfloat16 b = __float2bfloat16(f);
    return *reinterpret_cast<ushort*>(&b);
}
__device__ inline float bf2f(ushort u) {
    __hip_bfloat16 b;
    *reinterpret_cast<ushort*>(&b) = u;
    return __bfloat162float(b);
}

__device__ __forceinline__ void gload16(const void* g, void* l) {
    __builtin_amdgcn_global_load_lds(
        (const __attribute__((address_space(1))) void*)g,
        (__attribute__((address_space(3))) void*)l, 16, 0, 0);
}

// ---------------- CSR build (edge_index is int32 from harness) ----------------

__global__ void k_count(const int* __restrict__ ei, unsigned* __restrict__ cnt) {
    int e = blockIdx.x * blockDim.x + threadIdx.x;
    if (e < NE) atomicAdd(&cnt[ei[NE + e]], 1u);
}

__global__ void k_dinv(const unsigned* __restrict__ cnt, float* __restrict__ dinv) {
    int i = blockIdx.x * blockDim.x + threadIdx.x;
    if (i < NN) dinv[i] = rsqrtf((float)(cnt[i] + 1u));  // deg includes self-loop
}

// --- hierarchical exclusive scan ---

__global__ __launch_bounds__(1024) void k_scan1(const unsigned* __restrict__ cnt,
                                                unsigned* __restrict__ offs,
                                                unsigned* __restrict__ bsum) {
    __shared__ unsigned sh[1024];
    int i = blockIdx.x * 1024 + (int)threadIdx.x;
    unsigned v = (i < NN) ? cnt[i] : 0u;
    sh[threadIdx.x] = v;
    __syncthreads();
    #pragma unroll
    for (int off = 1; off < 1024; off <<= 1) {
        unsigned add = (threadIdx.x >= (unsigned)off) ? sh[threadIdx.x - off] : 0u;
        __syncthreads();
        sh[threadIdx.x] += add;
        __syncthreads();
    }
    if (i < NN) offs[i] = sh[threadIdx.x] - v;  // block-local exclusive
    if (threadIdx.x == 1023) bsum[blockIdx.x] = sh[1023];
}

__global__ void k_scan2(const unsigned* __restrict__ bsum, unsigned* __restrict__ boff,
                        unsigned* __restrict__ offs) {
    if (threadIdx.x == 0) {
        unsigned acc = 0;
        for (int b = 0; b < NB; ++b) { boff[b] = acc; acc += bsum[b]; }
        offs[NN] = acc;  // == NE
    }
}

__global__ __launch_bounds__(1024) void k_scan3(unsigned* __restrict__ offs,
                                                const unsigned* __restrict__ boff) {
    int i = blockIdx.x * 1024 + (int)threadIdx.x;
    if (i < NN) offs[i] += boff[blockIdx.x];
}

__global__ void k_fill(const int* __restrict__ ei, const unsigned* __restrict__ offs,
                       unsigned* __restrict__ cursor, const float* __restrict__ dinv,
                       unsigned* __restrict__ csr_src, float* __restrict__ csr_w) {
    int e = blockIdx.x * blockDim.x + threadIdx.x;
    if (e < NE) {
        int s = ei[e];
        int d = ei[NE + e];
        unsigned pos = offs[d] + atomicAdd(&cursor[d], 1u);
        csr_src[pos] = (unsigned)s;
        csr_w[pos] = dinv[s] * dinv[d];
    }
}

// -------- Weight cast+transpose: W[K][N] fp32 -> Wt [N][K] bf16 (hi only) --------

__global__ void k_castW(const float* __restrict__ W, ushort* __restrict__ Wt, int K, int N) {
    int i = blockIdx.x * 256 + (int)threadIdx.x;
    if (i >= K * N) return;
    int k = i / N, n = i - k * N;
    Wt[n * K + k] = f2bf(W[i]);
}

// ------- Aggregation: y = A_hat * x, emitted as split bf16 hi/lo -------

template <int VEC>
__global__ __launch_bounds__(256) void k_aggregate(
        const float* __restrict__ x, ushort* __restrict__ yh, ushort* __restrict__ yl,
        const unsigned* __restrict__ offs, const unsigned* __restrict__ csr_src,
        const float* __restrict__ csr_w, const float* __restrict__ dinv) {
    const int F = 64 * VEC;
    int node = blockIdx.x * 4 + ((int)threadIdx.x >> 6);
    int lane = (int)threadIdx.x & 63;
    if (node >= NN) return;

    float di = dinv[node];
    float sw = di * di;
    float acc[VEC];
    const float* xs = x + (size_t)node * F + lane * VEC;
    if constexpr (VEC == 2) {
        float2 v = *reinterpret_cast<const float2*>(xs);
        acc[0] = sw * v.x; acc[1] = sw * v.y;
    } else {
        float4 v = *reinterpret_cast<const float4*>(xs);
        acc[0] = sw * v.x; acc[1] = sw * v.y; acc[2] = sw * v.z; acc[3] = sw * v.w;
    }

    unsigned beg = offs[node], end = offs[node + 1];
    for (unsigned idx = beg; idx < end; ++idx) {
        unsigned s = csr_src[idx];
        float w = csr_w[idx];
        const float* xr = x + (size_t)s * F + lane * VEC;
        if constexpr (VEC == 2) {
            float2 v = *reinterpret_cast<const float2*>(xr);
            acc[0] = fmaf(w, v.x, acc[0]); acc[1] = fmaf(w, v.y, acc[1]);
        } else {
            float4 v = *reinterpret_cast<const float4*>(xr);
            acc[0] = fmaf(w, v.x, acc[0]); acc[1] = fmaf(w, v.y, acc[1]);
            acc[2] = fmaf(w, v.z, acc[2]); acc[3] = fmaf(w, v.w, acc[3]);
        }
    }

    size_t ybase = (size_t)node * F + lane * VEC;
    ushort h[VEC], l[VEC];
    #pragma unroll
    for (int j = 0; j < VEC; ++j) {
        h[j] = f2bf(acc[j]);
        l[j] = f2bf(acc[j] - bf2f(h[j]));
    }
    if constexpr (VEC == 2) {
        *reinterpret_cast<ushort2*>(yh + ybase) = make_ushort2(h[0], h[1]);
        *reinterpret_cast<ushort2*>(yl + ybase) = make_ushort2(l[0], l[1]);
    } else {
        *reinterpret_cast<ushort4*>(yh + ybase) = make_ushort4(h[0], h[1], h[2], h[3]);
        *reinterpret_cast<ushort4*>(yl + ybase) = make_ushort4(l[0], l[1], l[2], l[3]);
    }
}

// ------- GEMM v3: B-resident-in-LDS, A direct-to-register, no main-loop barriers -------
// C = relu(A[M,K] @ W[K,N] + bias). A as Ah/Al [M][K] bf16; W as Wt [N][K] bf16.
// Block: 256 rows x 128 cols, 4 waves each 64x128 (mi=4, ni=8).
// B slice (K x 128, 32-64KB) loaded once into LDS, kg-major chunks:
//   sB[((t*4+kg)*128 + n)*8] <- Wt[(col0+n)*K + t*32 + kg*8], 16B chunks.
// K-loop: A frags loaded global->reg with explicit 2-stage pipeline; B via
// ds_read_b128 (16 consecutive n per 16-lane group -> conflict-free, proven R4/5).

template <int NT, int SC>  // K = NT*32 ; SC = N/128
__global__ __launch_bounds__(256, 2) void k_gemm3(
        const ushort* __restrict__ Ah, const ushort* __restrict__ Al,
        const ushort* __restrict__ Wt, const float* __restrict__ bias,
        float* __restrict__ C, int M, int N) {
    constexpr int K = NT * 32;
    __shared__ __align__(16) short sB[NT * 512 * 8];  // K*128 bf16 = NT*8KB

    // bijective XCD swizzle: adjacent swz share 'by' (same A rows) within an XCD chunk
    int nwg = (int)gridDim.x;
    int bid = (int)blockIdx.x;
    int q = nwg >> 3, r = nwg & 7;
    int xcd = bid & 7, seq = bid >> 3;
    int swz = (xcd < r ? xcd * (q + 1) : r * (q + 1) + (xcd - r) * q) + seq;
    int bx = swz % SC, by = swz / SC;
    int col0 = bx * 128, row0 = by * 256;

    int tid = (int)threadIdx.x;
    int w = tid >> 6, lane = tid & 63;
    int r16 = lane & 15, kg = lane >> 4;

    // stage B once (NT*2 chunks of 16B per thread)
    #pragma unroll
    for (int i = 0; i < NT * 2; ++i) {
        int c = i * 256 + tid;
        int t = c >> 9, rem = c & 511;
        int ckg = rem >> 7, n = rem & 127;
        gload16(Wt + (size_t)(col0 + n) * K + t * 32 + ckg * 8, sB + c * 8);
    }
    __syncthreads();  // only barrier in the kernel

    size_t aoff[4];
    #pragma unroll
    for (int mi = 0; mi < 4; ++mi) {
        int row = row0 + w * 64 + mi * 16 + r16;
        if (row >= M) row = M - 1;  // clamp reads; stores guarded
        aoff[mi] = (size_t)row * K + kg * 8;
    }

    f32x4 acc[4][8] = {};
    bf16x8 ah[2][4], al[2][4];  // 2-stage pipeline, static-indexed via full unroll

    #pragma unroll
    for (int mi = 0; mi < 4; ++mi) {
        ah[0][mi] = *reinterpret_cast<const bf16x8*>(Ah + aoff[mi]);
        al[0][mi] = *reinterpret_cast<const bf16x8*>(Al + aoff[mi]);
    }

    #pragma unroll
    for (int t = 0; t < NT; ++t) {
        const int cur = t & 1;
        if (t + 1 < NT) {
            #pragma unroll
            for (int mi = 0; mi < 4; ++mi) {
                ah[cur ^ 1][mi] = *reinterpret_cast<const bf16x8*>(Ah + aoff[mi] + (t + 1) * 32);
                al[cur ^ 1][mi] = *reinterpret_cast<const bf16x8*>(Al + aoff[mi] + (t + 1) * 32);
            }
        }
        #pragma unroll
        for (int ni = 0; ni < 8; ++ni) {
            bf16x8 bb = *reinterpret_cast<const bf16x8*>(sB + ((t * 4 + kg) * 128 + ni * 16 + r16) * 8);
            #pragma unroll
            for (int mi = 0; mi < 4; ++mi) {
                acc[mi][ni] = __builtin_amdgcn_mfma_f32_16x16x32_bf16(ah[cur][mi], bb, acc[mi][ni], 0, 0, 0);
                acc[mi][ni] = __builtin_amdgcn_mfma_f32_16x16x32_bf16(al[cur][mi], bb, acc[mi][ni], 0, 0, 0);
            }
        }
    }

    // epilogue: D lane l -> col = l&15, row = (l>>4)*4 + j
    int crow0 = (lane >> 4) * 4;
    int ccol = lane & 15;
    int rb = row0 + w * 64;
    #pragma unroll
    for (int ni = 0; ni < 8; ++ni) {
        int col = col0 + ni * 16 + ccol;
        float bv = bias[col];
        #pragma unroll
        for (int mi = 0; mi < 4; ++mi)
            #pragma unroll
            for (int j = 0; j < 4; ++j) {
                int row = rb + mi * 16 + crow0 + j;
                if (row < M)
                    C[(size_t)row * N + col] = fmaxf(acc[mi][ni][j] + bv, 0.f);
            }
    }
}

// ---------------- launch ----------------

extern "C" void kernel_launch(void* const* d_in, const int* in_sizes, int n_in,
                              void* d_out, int out_size, void* d_ws, size_t ws_size,
                              hipStream_t stream) {
    const float* v  = (const float*)d_in[0];
    const int* ei   = (const int*)d_in[1];
    const float* W1 = (const float*)d_in[2];
    const float* b1 = (const float*)d_in[3];
    const float* W2 = (const float*)d_in[4];
    const float* b2 = (const float*)d_in[5];
    const float* W3 = (const float*)d_in[6];
    const float* b3 = (const float*)d_in[7];
    float* out = (float*)d_out;

    char* ws = (char*)d_ws;
    size_t off = 0;
    auto alloc = [&](size_t bytes) {
        void* p = ws + off;
        off = (off + bytes + 255) & ~(size_t)255;
        return p;
    };
    // cnt+cursor at front; dead after k_fill -> overlaid by Wt1/Wt2 (96KB <= 400KB).
    unsigned* cnt    = (unsigned*)(ws + 0);
    unsigned* cursor = (unsigned*)(ws + (size_t)NN * 4);
    ushort* Wt1 = (ushort*)ws;               // [128][128] = 32KB
    ushort* Wt2 = Wt1 + 128 * 128;           // [256][128] = 64KB
    off = ((size_t)NN * 8 + 255) & ~(size_t)255;
    unsigned* offs    = (unsigned*)alloc((size_t)(NN + 1) * 4);
    float*    dinv    = (float*)alloc((size_t)NN * 4);
    unsigned* bsum    = (unsigned*)alloc((size_t)NB * 4);
    unsigned* boff    = (unsigned*)alloc((size_t)NB * 4);
    unsigned* csr_src = (unsigned*)alloc((size_t)NE * 4);
    float*    csr_w   = (float*)alloc((size_t)NE * 4);
    // csr_src dead after agg3 -> overlaid by Wt3 [512][256] = 256KB <= 1.6MB.
    ushort* Wt3 = (ushort*)csr_src;
    ushort* aggAh = (ushort*)alloc((size_t)NN * 256 * 2);
    ushort* aggAl = (ushort*)alloc((size_t)NN * 256 * 2);
    float* bufB = out;  // fp32 activations alias d_out (consumed before final GEMM writes)

    hipMemsetAsync(cnt, 0, (size_t)NN * 8, stream);  // cnt + cursor

    k_count<<<(NE + 255) / 256, 256, 0, stream>>>(ei, cnt);
    k_dinv<<<(NN + 255) / 256, 256, 0, stream>>>(cnt, dinv);
    k_scan1<<<NB, 1024, 0, stream>>>(cnt, offs, bsum);
    k_scan2<<<1, 64, 0, stream>>>(bsum, boff, offs);
    k_scan3<<<NB, 1024, 0, stream>>>(offs, boff);
    k_fill<<<(NE + 255) / 256, 256, 0, stream>>>(ei, offs, cursor, dinv, csr_src, csr_w);

    // Weight casts (after k_fill: cnt/cursor region is dead)
    k_castW<<<(128 * 128 + 255) / 256, 256, 0, stream>>>(W1, Wt1, 128, 128);
    k_castW<<<(128 * 256 + 255) / 256, 256, 0, stream>>>(W2, Wt2, 128, 256);

    int aggGrid = (NN + 3) / 4;
    int gr = (NN + 255) / 256;  // 196 row-tiles

    // Layer 1: agg(v) -> split bf16 ; GEMM K=128,N=128 -> x1 (fp32)
    k_aggregate<2><<<aggGrid, 256, 0, stream>>>(v, aggAh, aggAl, offs, csr_src, csr_w, dinv);
    k_gemm3<4, 1><<<gr * 1, 256, 0, stream>>>(aggAh, aggAl, Wt1, b1, bufB, NN, 128);

    // Layer 2: agg(x1) ; GEMM K=128,N=256 -> x2 (fp32)
    k_aggregate<2><<<aggGrid, 256, 0, stream>>>(bufB, aggAh, aggAl, offs, csr_src, csr_w, dinv);
    k_gemm3<4, 2><<<gr * 2, 256, 0, stream>>>(aggAh, aggAl, Wt2, b2, bufB, NN, 256);

    // Layer 3: agg(x2) ; cast W3 (csr_src now dead) ; GEMM K=256,N=512 -> out
    k_aggregate<4><<<aggGrid, 256, 0, stream>>>(bufB, aggAh, aggAl, offs, csr_src, csr_w, dinv);
    k_castW<<<(256 * 512 + 255) / 256, 256, 0, stream>>>(W3, Wt3, 256, 512);
    k_gemm3<8, 4><<<gr * 4, 256, 0, stream>>>(aggAh, aggAl, Wt3, b3, out, NN, 512);
}

// Round 7
// 338.097 us; speedup vs baseline: 1.0873x; 1.0873x over previous
//
#include <hip/hip_runtime.h>
#include <hip/hip_bf16.h>
#include <stdint.h>

static constexpr int NN = 50000;   // nodes
static constexpr int NE = 400000;  // edges
static constexpr int NB = (NN + 1023) / 1024;  // 49 scan blocks

typedef __attribute__((ext_vector_type(8))) short bf16x8;
typedef __attribute__((ext_vector_type(4))) float f32x4;

__device__ inline ushort f2bf(float f) {
    __hip_bfloat16 b = __float2bfloat16(f);
    return *reinterpret_cast<ushort*>(&b);
}

__device__ __forceinline__ void gload16(const void* g, void* l) {
    __builtin_amdgcn_global_load_lds(
        (const __attribute__((address_space(1))) void*)g,
        (__attribute__((address_space(3))) void*)l, 16, 0, 0);
}

// ---------------- CSR build (edge_index is int32 from harness) ----------------

__global__ void k_count(const int* __restrict__ ei, unsigned* __restrict__ cnt) {
    int e = blockIdx.x * blockDim.x + threadIdx.x;
    if (e < NE) atomicAdd(&cnt[ei[NE + e]], 1u);
}

__global__ void k_dinv(const unsigned* __restrict__ cnt, float* __restrict__ dinv) {
    int i = blockIdx.x * blockDim.x + threadIdx.x;
    if (i < NN) dinv[i] = rsqrtf((float)(cnt[i] + 1u));  // deg includes self-loop
}

// --- hierarchical exclusive scan ---

__global__ __launch_bounds__(1024) void k_scan1(const unsigned* __restrict__ cnt,
                                                unsigned* __restrict__ offs,
                                                unsigned* __restrict__ bsum) {
    __shared__ unsigned sh[1024];
    int i = blockIdx.x * 1024 + (int)threadIdx.x;
    unsigned v = (i < NN) ? cnt[i] : 0u;
    sh[threadIdx.x] = v;
    __syncthreads();
    #pragma unroll
    for (int off = 1; off < 1024; off <<= 1) {
        unsigned add = (threadIdx.x >= (unsigned)off) ? sh[threadIdx.x - off] : 0u;
        __syncthreads();
        sh[threadIdx.x] += add;
        __syncthreads();
    }
    if (i < NN) offs[i] = sh[threadIdx.x] - v;  // block-local exclusive
    if (threadIdx.x == 1023) bsum[blockIdx.x] = sh[1023];
}

__global__ void k_scan2(const unsigned* __restrict__ bsum, unsigned* __restrict__ boff,
                        unsigned* __restrict__ offs) {
    if (threadIdx.x == 0) {
        unsigned acc = 0;
        for (int b = 0; b < NB; ++b) { boff[b] = acc; acc += bsum[b]; }
        offs[NN] = acc;  // == NE
    }
}

__global__ __launch_bounds__(1024) void k_scan3(unsigned* __restrict__ offs,
                                                const unsigned* __restrict__ boff) {
    int i = blockIdx.x * 1024 + (int)threadIdx.x;
    if (i < NN) offs[i] += boff[blockIdx.x];
}

__global__ void k_fill(const int* __restrict__ ei, const unsigned* __restrict__ offs,
                       unsigned* __restrict__ cursor, const float* __restrict__ dinv,
                       unsigned* __restrict__ csr_src, float* __restrict__ csr_w) {
    int e = blockIdx.x * blockDim.x + threadIdx.x;
    if (e < NE) {
        int s = ei[e];
        int d = ei[NE + e];
        unsigned pos = offs[d] + atomicAdd(&cursor[d], 1u);
        csr_src[pos] = (unsigned)s;
        csr_w[pos] = dinv[s] * dinv[d];
    }
}

// -------- Weight cast+transpose: W[K][N] fp32 -> Wt [N][K] bf16 --------

__global__ void k_castW(const float* __restrict__ W, ushort* __restrict__ Wt, int K, int N) {
    int i = blockIdx.x * 256 + (int)threadIdx.x;
    if (i >= K * N) return;
    int k = i / N, n = i - k * N;
    Wt[n * K + k] = f2bf(W[i]);
}

// ------- Aggregation: y = A_hat * x, emitted as bf16 -------

template <int VEC>
__global__ __launch_bounds__(256) void k_aggregate(
        const float* __restrict__ x, ushort* __restrict__ yh,
        const unsigned* __restrict__ offs, const unsigned* __restrict__ csr_src,
        const float* __restrict__ csr_w, const float* __restrict__ dinv) {
    const int F = 64 * VEC;
    int node = blockIdx.x * 4 + ((int)threadIdx.x >> 6);
    int lane = (int)threadIdx.x & 63;
    if (node >= NN) return;

    float di = dinv[node];
    float sw = di * di;
    float acc[VEC];
    const float* xs = x + (size_t)node * F + lane * VEC;
    if constexpr (VEC == 2) {
        float2 v = *reinterpret_cast<const float2*>(xs);
        acc[0] = sw * v.x; acc[1] = sw * v.y;
    } else {
        float4 v = *reinterpret_cast<const float4*>(xs);
        acc[0] = sw * v.x; acc[1] = sw * v.y; acc[2] = sw * v.z; acc[3] = sw * v.w;
    }

    unsigned beg = offs[node], end = offs[node + 1];
    for (unsigned idx = beg; idx < end; ++idx) {
        unsigned s = csr_src[idx];
        float w = csr_w[idx];
        const float* xr = x + (size_t)s * F + lane * VEC;
        if constexpr (VEC == 2) {
            float2 v = *reinterpret_cast<const float2*>(xr);
            acc[0] = fmaf(w, v.x, acc[0]); acc[1] = fmaf(w, v.y, acc[1]);
        } else {
            float4 v = *reinterpret_cast<const float4*>(xr);
            acc[0] = fmaf(w, v.x, acc[0]); acc[1] = fmaf(w, v.y, acc[1]);
            acc[2] = fmaf(w, v.z, acc[2]); acc[3] = fmaf(w, v.w, acc[3]);
        }
    }

    size_t ybase = (size_t)node * F + lane * VEC;
    ushort h[VEC];
    #pragma unroll
    for (int j = 0; j < VEC; ++j) h[j] = f2bf(acc[j]);
    if constexpr (VEC == 2) {
        *reinterpret_cast<ushort2*>(yh + ybase) = make_ushort2(h[0], h[1]);
    } else {
        *reinterpret_cast<ushort4*>(yh + ybase) = make_ushort4(h[0], h[1], h[2], h[3]);
    }
}

// ------- GEMM v4: bf16 A (no split), B-in-LDS K-chunked, 64x64 wave tiles -------
// C = relu(A[M,K] @ W[K,N] + bias). A [M][K] bf16; W as Wt [N][K] bf16.
// Block: 256 thr = 4 waves (2x2), tile 128x128, wave 64x64 (acc 64 regs).
// B chunk (128-K x 128-N = 32KB) staged kg-major; restaged K/128 times.
// A: global->reg 2-stage pipeline. __launch_bounds__(256,3) -> 12 waves/CU.

template <int NT, int SC>  // K = NT*32 ; SC = N/128
__global__ __launch_bounds__(256, 3) void k_gemm4(
        const ushort* __restrict__ Ah, const ushort* __restrict__ Wt,
        const float* __restrict__ bias, float* __restrict__ C, int M, int N) {
    constexpr int K = NT * 32;
    constexpr int CHT = (NT > 4) ? 4 : NT;   // K-steps per staged chunk
    constexpr int NCH = NT / CHT;            // chunks
    __shared__ __align__(16) short sB[CHT * 512 * 8];  // 32KB (CHT=4)

    // bijective XCD swizzle
    int nwg = (int)gridDim.x;
    int bid = (int)blockIdx.x;
    int q = nwg >> 3, r = nwg & 7;
    int xcd = bid & 7, seq = bid >> 3;
    int swz = (xcd < r ? xcd * (q + 1) : r * (q + 1) + (xcd - r) * q) + seq;
    int bx = swz % SC, by = swz / SC;
    int col0 = bx * 128, row0 = by * 128;

    int tid = (int)threadIdx.x;
    int w = tid >> 6, lane = tid & 63;
    int wr = w >> 1, wc = w & 1;
    int r16 = lane & 15, kg = lane >> 4;

    size_t aoff[4];
    #pragma unroll
    for (int mi = 0; mi < 4; ++mi) {
        int row = row0 + wr * 64 + mi * 16 + r16;
        if (row >= M) row = M - 1;  // clamp reads; stores guarded
        aoff[mi] = (size_t)row * K + kg * 8;
    }

    f32x4 acc[4][4] = {};
    bf16x8 ah[2][4];  // 2-stage A pipeline (static-indexed, fully unrolled)

    #pragma unroll
    for (int mi = 0; mi < 4; ++mi)
        ah[0][mi] = *reinterpret_cast<const bf16x8*>(Ah + aoff[mi]);

    #pragma unroll
    for (int kc = 0; kc < NCH; ++kc) {
        if (kc) __syncthreads();  // prev chunk fully consumed before overwrite
        // stage B chunk: CHT*512 16B-chunks, CHT*2 per thread
        #pragma unroll
        for (int i = 0; i < CHT * 2; ++i) {
            int c = i * 256 + tid;
            int tl = c >> 9, ckg = (c >> 7) & 3, n = c & 127;
            gload16(Wt + (size_t)(col0 + n) * K + (kc * CHT + tl) * 32 + ckg * 8,
                    sB + c * 8);
        }
        __syncthreads();

        #pragma unroll
        for (int t = 0; t < CHT; ++t) {
            int tg = kc * CHT + t;
            const int cur = tg & 1;
            if (tg + 1 < NT) {
                #pragma unroll
                for (int mi = 0; mi < 4; ++mi)
                    ah[cur ^ 1][mi] = *reinterpret_cast<const bf16x8*>(Ah + aoff[mi] + (tg + 1) * 32);
            }
            bf16x8 bb[4];
            #pragma unroll
            for (int ni = 0; ni < 4; ++ni)
                bb[ni] = *reinterpret_cast<const bf16x8*>(
                    sB + ((t * 4 + kg) * 128 + wc * 64 + ni * 16 + r16) * 8);
            #pragma unroll
            for (int ni = 0; ni < 4; ++ni)
                #pragma unroll
                for (int mi = 0; mi < 4; ++mi)
                    acc[mi][ni] = __builtin_amdgcn_mfma_f32_16x16x32_bf16(ah[cur][mi], bb[ni], acc[mi][ni], 0, 0, 0);
        }
    }

    // epilogue: D lane l -> col = l&15, row = (l>>4)*4 + j
    int crow0 = (lane >> 4) * 4;
    int ccol = lane & 15;
    int rb = row0 + wr * 64;
    int cb = col0 + wc * 64;
    #pragma unroll
    for (int ni = 0; ni < 4; ++ni) {
        int col = cb + ni * 16 + ccol;
        float bv = bias[col];
        #pragma unroll
        for (int mi = 0; mi < 4; ++mi)
            #pragma unroll
            for (int j = 0; j < 4; ++j) {
                int row = rb + mi * 16 + crow0 + j;
                if (row < M)
                    C[(size_t)row * N + col] = fmaxf(acc[mi][ni][j] + bv, 0.f);
            }
    }
}

// ---------------- launch ----------------

extern "C" void kernel_launch(void* const* d_in, const int* in_sizes, int n_in,
                              void* d_out, int out_size, void* d_ws, size_t ws_size,
                              hipStream_t stream) {
    const float* v  = (const float*)d_in[0];
    const int* ei   = (const int*)d_in[1];
    const float* W1 = (const float*)d_in[2];
    const float* b1 = (const float*)d_in[3];
    const float* W2 = (const float*)d_in[4];
    const float* b2 = (const float*)d_in[5];
    const float* W3 = (const float*)d_in[6];
    const float* b3 = (const float*)d_in[7];
    float* out = (float*)d_out;

    char* ws = (char*)d_ws;
    size_t off = 0;
    auto alloc = [&](size_t bytes) {
        void* p = ws + off;
        off = (off + bytes + 255) & ~(size_t)255;
        return p;
    };
    // cnt+cursor at front; dead after k_fill -> overlaid by Wt1/Wt2 (96KB <= 400KB).
    unsigned* cnt    = (unsigned*)(ws + 0);
    unsigned* cursor = (unsigned*)(ws + (size_t)NN * 4);
    ushort* Wt1 = (ushort*)ws;               // [128][128] = 32KB
    ushort* Wt2 = Wt1 + 128 * 128;           // [256][128] = 64KB
    off = ((size_t)NN * 8 + 255) & ~(size_t)255;
    unsigned* offs    = (unsigned*)alloc((size_t)(NN + 1) * 4);
    float*    dinv    = (float*)alloc((size_t)NN * 4);
    unsigned* bsum    = (unsigned*)alloc((size_t)NB * 4);
    unsigned* boff    = (unsigned*)alloc((size_t)NB * 4);
    unsigned* csr_src = (unsigned*)alloc((size_t)NE * 4);
    float*    csr_w   = (float*)alloc((size_t)NE * 4);
    // csr_src dead after agg3 -> overlaid by Wt3 [512][256] = 256KB <= 1.6MB.
    ushort* Wt3 = (ushort*)csr_src;
    ushort* aggA = (ushort*)alloc((size_t)NN * 256 * 2);
    float* bufB = out;  // fp32 activations alias d_out (consumed before final GEMM writes)

    hipMemsetAsync(cnt, 0, (size_t)NN * 8, stream);  // cnt + cursor

    k_count<<<(NE + 255) / 256, 256, 0, stream>>>(ei, cnt);
    k_dinv<<<(NN + 255) / 256, 256, 0, stream>>>(cnt, dinv);
    k_scan1<<<NB, 1024, 0, stream>>>(cnt, offs, bsum);
    k_scan2<<<1, 64, 0, stream>>>(bsum, boff, offs);
    k_scan3<<<NB, 1024, 0, stream>>>(offs, boff);
    k_fill<<<(NE + 255) / 256, 256, 0, stream>>>(ei, offs, cursor, dinv, csr_src, csr_w);

    // Weight casts (after k_fill: cnt/cursor region is dead)
    k_castW<<<(128 * 128 + 255) / 256, 256, 0, stream>>>(W1, Wt1, 128, 128);
    k_castW<<<(128 * 256 + 255) / 256, 256, 0, stream>>>(W2, Wt2, 128, 256);

    int aggGrid = (NN + 3) / 4;
    int gr = (NN + 127) / 128;  // 391 row-tiles

    // Layer 1: agg(v) -> bf16 ; GEMM K=128,N=128 -> x1 (fp32)
    k_aggregate<2><<<aggGrid, 256, 0, stream>>>(v, aggA, offs, csr_src, csr_w, dinv);
    k_gemm4<4, 1><<<gr * 1, 256, 0, stream>>>(aggA, Wt1, b1, bufB, NN, 128);

    // Layer 2: agg(x1) ; GEMM K=128,N=256 -> x2 (fp32)
    k_aggregate<2><<<aggGrid, 256, 0, stream>>>(bufB, aggA, offs, csr_src, csr_w, dinv);
    k_gemm4<4, 2><<<gr * 2, 256, 0, stream>>>(aggA, Wt2, b2, bufB, NN, 256);

    // Layer 3: agg(x2) ; cast W3 (csr_src now dead) ; GEMM K=256,N=512 -> out
    k_aggregate<4><<<aggGrid, 256, 0, stream>>>(bufB, aggA, offs, csr_src, csr_w, dinv);
    k_castW<<<(256 * 512 + 255) / 256, 256, 0, stream>>>(W3, Wt3, 256, 512);
    k_gemm4<8, 4><<<gr * 4, 256, 0, stream>>>(aggA, Wt3, b3, out, NN, 512);
}

// Round 8
// 277.153 us; speedup vs baseline: 1.3264x; 1.2199x over previous
//
#include <hip/hip_runtime.h>
#include <hip/hip_bf16.h>
#include <stdint.h>

static constexpr int NN = 50000;   // nodes
static constexpr int NE = 400000;  // edges
static constexpr int NB = (NN + 1023) / 1024;  // 49 scan blocks

typedef __attribute__((ext_vector_type(8))) short bf16x8;
typedef __attribute__((ext_vector_type(4))) float f32x4;

__device__ inline ushort f2bf(float f) {
    __hip_bfloat16 b = __float2bfloat16(f);
    return *reinterpret_cast<ushort*>(&b);
}
__device__ inline float bfu2f(ushort u) {
    unsigned x = (unsigned)u << 16;
    return __builtin_bit_cast(float, x);
}

__device__ __forceinline__ void gload16(const void* g, void* l) {
    __builtin_amdgcn_global_load_lds(
        (const __attribute__((address_space(1))) void*)g,
        (__attribute__((address_space(3))) void*)l, 16, 0, 0);
}

// ---------------- CSR build (edge_index is int32 from harness) ----------------

__global__ void k_count(const int* __restrict__ ei, unsigned* __restrict__ cnt) {
    int e = blockIdx.x * blockDim.x + threadIdx.x;
    if (e < NE) atomicAdd(&cnt[ei[NE + e]], 1u);
}

__global__ void k_dinv(const unsigned* __restrict__ cnt, float* __restrict__ dinv) {
    int i = blockIdx.x * blockDim.x + threadIdx.x;
    if (i < NN) dinv[i] = rsqrtf((float)(cnt[i] + 1u));  // deg includes self-loop
}

// --- hierarchical exclusive scan ---

__global__ __launch_bounds__(1024) void k_scan1(const unsigned* __restrict__ cnt,
                                                unsigned* __restrict__ offs,
                                                unsigned* __restrict__ bsum) {
    __shared__ unsigned sh[1024];
    int i = blockIdx.x * 1024 + (int)threadIdx.x;
    unsigned v = (i < NN) ? cnt[i] : 0u;
    sh[threadIdx.x] = v;
    __syncthreads();
    #pragma unroll
    for (int off = 1; off < 1024; off <<= 1) {
        unsigned add = (threadIdx.x >= (unsigned)off) ? sh[threadIdx.x - off] : 0u;
        __syncthreads();
        sh[threadIdx.x] += add;
        __syncthreads();
    }
    if (i < NN) offs[i] = sh[threadIdx.x] - v;  // block-local exclusive
    if (threadIdx.x == 1023) bsum[blockIdx.x] = sh[1023];
}

__global__ void k_scan2(const unsigned* __restrict__ bsum, unsigned* __restrict__ boff,
                        unsigned* __restrict__ offs) {
    if (threadIdx.x == 0) {
        unsigned acc = 0;
        for (int b = 0; b < NB; ++b) { boff[b] = acc; acc += bsum[b]; }
        offs[NN] = acc;  // == NE
    }
}

__global__ __launch_bounds__(1024) void k_scan3(unsigned* __restrict__ offs,
                                                const unsigned* __restrict__ boff) {
    int i = blockIdx.x * 1024 + (int)threadIdx.x;
    if (i < NN) offs[i] += boff[blockIdx.x];
}

__global__ void k_fill(const int* __restrict__ ei, const unsigned* __restrict__ offs,
                       unsigned* __restrict__ cursor, const float* __restrict__ dinv,
                       unsigned* __restrict__ csr_src, float* __restrict__ csr_w) {
    int e = blockIdx.x * blockDim.x + threadIdx.x;
    if (e < NE) {
        int s = ei[e];
        int d = ei[NE + e];
        unsigned pos = offs[d] + atomicAdd(&cursor[d], 1u);
        csr_src[pos] = (unsigned)s;
        csr_w[pos] = dinv[s] * dinv[d];
    }
}

// -------- Weight cast+transpose: W[K][N] fp32 -> Wt [N][K] bf16 --------

__global__ void k_castW(const float* __restrict__ W, ushort* __restrict__ Wt, int K, int N) {
    int i = blockIdx.x * 256 + (int)threadIdx.x;
    if (i >= K * N) return;
    int k = i / N, n = i - k * N;
    Wt[n * K + k] = f2bf(W[i]);
}

// -------- v fp32 -> bf16 (vectorized) --------

__global__ void k_castV(const float* __restrict__ v, ushort* __restrict__ vb, int n4) {
    int i = blockIdx.x * 256 + (int)threadIdx.x;
    if (i >= n4) return;
    float4 f = *reinterpret_cast<const float4*>(v + (size_t)i * 4);
    *reinterpret_cast<ushort4*>(vb + (size_t)i * 4) =
        make_ushort4(f2bf(f.x), f2bf(f.y), f2bf(f.z), f2bf(f.w));
}

// ------- Aggregation: y = A_hat * x (x in bf16), emit bf16 -------
// one wave per node; VEC bf16/lane; F = 64*VEC. Edge loop unrolled x2.

template <int VEC>
__global__ __launch_bounds__(256) void k_aggregate(
        const ushort* __restrict__ x, ushort* __restrict__ y,
        const unsigned* __restrict__ offs, const unsigned* __restrict__ csr_src,
        const float* __restrict__ csr_w, const float* __restrict__ dinv) {
    const int F = 64 * VEC;
    int node = blockIdx.x * 4 + ((int)threadIdx.x >> 6);
    int lane = (int)threadIdx.x & 63;
    if (node >= NN) return;

    float di = dinv[node];
    float sw = di * di;
    float acc[VEC];
    const ushort* xs = x + (size_t)node * F + lane * VEC;
    #pragma unroll
    for (int j = 0; j < VEC; ++j) acc[j] = sw * bfu2f(xs[j]);

    unsigned beg = offs[node], end = offs[node + 1];
    unsigned idx = beg;
    for (; idx + 1 < end; idx += 2) {
        unsigned s0 = csr_src[idx], s1 = csr_src[idx + 1];
        float w0 = csr_w[idx], w1 = csr_w[idx + 1];
        const ushort* x0 = x + (size_t)s0 * F + lane * VEC;
        const ushort* x1 = x + (size_t)s1 * F + lane * VEC;
        ushort u0[VEC], u1[VEC];
        if constexpr (VEC == 2) {
            *reinterpret_cast<ushort2*>(u0) = *reinterpret_cast<const ushort2*>(x0);
            *reinterpret_cast<ushort2*>(u1) = *reinterpret_cast<const ushort2*>(x1);
        } else {
            *reinterpret_cast<ushort4*>(u0) = *reinterpret_cast<const ushort4*>(x0);
            *reinterpret_cast<ushort4*>(u1) = *reinterpret_cast<const ushort4*>(x1);
        }
        #pragma unroll
        for (int j = 0; j < VEC; ++j) {
            acc[j] = fmaf(w0, bfu2f(u0[j]), acc[j]);
            acc[j] = fmaf(w1, bfu2f(u1[j]), acc[j]);
        }
    }
    if (idx < end) {
        unsigned s0 = csr_src[idx];
        float w0 = csr_w[idx];
        const ushort* x0 = x + (size_t)s0 * F + lane * VEC;
        ushort u0[VEC];
        if constexpr (VEC == 2) {
            *reinterpret_cast<ushort2*>(u0) = *reinterpret_cast<const ushort2*>(x0);
        } else {
            *reinterpret_cast<ushort4*>(u0) = *reinterpret_cast<const ushort4*>(x0);
        }
        #pragma unroll
        for (int j = 0; j < VEC; ++j) acc[j] = fmaf(w0, bfu2f(u0[j]), acc[j]);
    }

    size_t ybase = (size_t)node * F + lane * VEC;
    ushort h[VEC];
    #pragma unroll
    for (int j = 0; j < VEC; ++j) h[j] = f2bf(acc[j]);
    if constexpr (VEC == 2) {
        *reinterpret_cast<ushort2*>(y + ybase) = make_ushort2(h[0], h[1]);
    } else {
        *reinterpret_cast<ushort4*>(y + ybase) = make_ushort4(h[0], h[1], h[2], h[3]);
    }
}

// ------- GEMM: bf16 A, B-in-LDS K-chunked, 64x64 wave tiles, 3-stage A pipeline -------
// C = relu(A[M,K] @ W[K,N] + bias); OUTB: write bf16, else fp32.

template <int NT, int SC, bool OUTB>  // K = NT*32 ; SC = N/128
__global__ __launch_bounds__(256, 3) void k_gemm5(
        const ushort* __restrict__ Ah, const ushort* __restrict__ Wt,
        const float* __restrict__ bias, void* __restrict__ Cout, int M, int N) {
    constexpr int K = NT * 32;
    constexpr int CHT = (NT > 4) ? 4 : NT;   // K-steps per staged chunk
    constexpr int NCH = NT / CHT;            // chunks
    __shared__ __align__(16) short sB[CHT * 512 * 8];  // 32KB (CHT=4)

    // bijective XCD swizzle
    int nwg = (int)gridDim.x;
    int bid = (int)blockIdx.x;
    int q = nwg >> 3, r = nwg & 7;
    int xcd = bid & 7, seq = bid >> 3;
    int swz = (xcd < r ? xcd * (q + 1) : r * (q + 1) + (xcd - r) * q) + seq;
    int bx = swz % SC, by = swz / SC;
    int col0 = bx * 128, row0 = by * 128;

    int tid = (int)threadIdx.x;
    int w = tid >> 6, lane = tid & 63;
    int wr = w >> 1, wc = w & 1;
    int r16 = lane & 15, kg = lane >> 4;

    size_t aoff[4];
    #pragma unroll
    for (int mi = 0; mi < 4; ++mi) {
        int row = row0 + wr * 64 + mi * 16 + r16;
        if (row >= M) row = M - 1;  // clamp reads; stores guarded
        aoff[mi] = (size_t)row * K + kg * 8;
    }

    f32x4 acc[4][4] = {};
    bf16x8 ah[3][4];  // 3-stage A pipeline (compile-time indexed: loops fully unrolled)

    #pragma unroll
    for (int mi = 0; mi < 4; ++mi)
        ah[0][mi] = *reinterpret_cast<const bf16x8*>(Ah + aoff[mi]);
    if constexpr (NT > 1) {
        #pragma unroll
        for (int mi = 0; mi < 4; ++mi)
            ah[1][mi] = *reinterpret_cast<const bf16x8*>(Ah + aoff[mi] + 32);
    }

    #pragma unroll
    for (int kc = 0; kc < NCH; ++kc) {
        if (kc) __syncthreads();  // prev chunk fully consumed before overwrite
        #pragma unroll
        for (int i = 0; i < CHT * 2; ++i) {
            int c = i * 256 + tid;
            int tl = c >> 9, ckg = (c >> 7) & 3, n = c & 127;
            gload16(Wt + (size_t)(col0 + n) * K + (kc * CHT + tl) * 32 + ckg * 8,
                    sB + c * 8);
        }
        __syncthreads();

        #pragma unroll
        for (int t = 0; t < CHT; ++t) {
            const int tg = kc * CHT + t;           // compile-time
            const int cur = tg % 3;
            if (tg + 2 < NT) {
                const int nxt = (tg + 2) % 3;
                #pragma unroll
                for (int mi = 0; mi < 4; ++mi)
                    ah[nxt][mi] = *reinterpret_cast<const bf16x8*>(Ah + aoff[mi] + (tg + 2) * 32);
            }
            bf16x8 bb[4];
            #pragma unroll
            for (int ni = 0; ni < 4; ++ni)
                bb[ni] = *reinterpret_cast<const bf16x8*>(
                    sB + ((t * 4 + kg) * 128 + wc * 64 + ni * 16 + r16) * 8);
            #pragma unroll
            for (int ni = 0; ni < 4; ++ni)
                #pragma unroll
                for (int mi = 0; mi < 4; ++mi)
                    acc[mi][ni] = __builtin_amdgcn_mfma_f32_16x16x32_bf16(ah[cur][mi], bb[ni], acc[mi][ni], 0, 0, 0);
        }
    }

    // epilogue: D lane l -> col = l&15, row = (l>>4)*4 + j
    int crow0 = (lane >> 4) * 4;
    int ccol = lane & 15;
    int rb = row0 + wr * 64;
    int cb = col0 + wc * 64;
    #pragma unroll
    for (int ni = 0; ni < 4; ++ni) {
        int col = cb + ni * 16 + ccol;
        float bv = bias[col];
        #pragma unroll
        for (int mi = 0; mi < 4; ++mi)
            #pragma unroll
            for (int j = 0; j < 4; ++j) {
                int row = rb + mi * 16 + crow0 + j;
                if (row < M) {
                    float val = fmaxf(acc[mi][ni][j] + bv, 0.f);
                    if constexpr (OUTB)
                        ((ushort*)Cout)[(size_t)row * N + col] = f2bf(val);
                    else
                        ((float*)Cout)[(size_t)row * N + col] = val;
                }
            }
    }
}

// ---------------- launch ----------------

extern "C" void kernel_launch(void* const* d_in, const int* in_sizes, int n_in,
                              void* d_out, int out_size, void* d_ws, size_t ws_size,
                              hipStream_t stream) {
    const float* v  = (const float*)d_in[0];
    const int* ei   = (const int*)d_in[1];
    const float* W1 = (const float*)d_in[2];
    const float* b1 = (const float*)d_in[3];
    const float* W2 = (const float*)d_in[4];
    const float* b2 = (const float*)d_in[5];
    const float* W3 = (const float*)d_in[6];
    const float* b3 = (const float*)d_in[7];
    float* out = (float*)d_out;

    char* ws = (char*)d_ws;
    size_t off = 0;
    auto alloc = [&](size_t bytes) {
        void* p = ws + off;
        off = (off + bytes + 255) & ~(size_t)255;
        return p;
    };
    // cnt+cursor at front; dead after k_fill -> overlaid by Wt1/Wt2 (96KB <= 400KB).
    unsigned* cnt    = (unsigned*)(ws + 0);
    unsigned* cursor = (unsigned*)(ws + (size_t)NN * 4);
    ushort* Wt1 = (ushort*)ws;               // [128][128] = 32KB
    ushort* Wt2 = Wt1 + 128 * 128;           // [256][128] = 64KB
    off = ((size_t)NN * 8 + 255) & ~(size_t)255;
    unsigned* offs    = (unsigned*)alloc((size_t)(NN + 1) * 4);
    float*    dinv    = (float*)alloc((size_t)NN * 4);
    unsigned* bsum    = (unsigned*)alloc((size_t)NB * 4);
    unsigned* boff    = (unsigned*)alloc((size_t)NB * 4);
    unsigned* csr_src = (unsigned*)alloc((size_t)NE * 4);
    float*    csr_w   = (float*)alloc((size_t)NE * 4);
    // csr_src dead after agg3 -> overlaid by Wt3 [512][256] = 256KB <= 1.6MB.
    ushort* Wt3 = (ushort*)csr_src;
    ushort* aggA = (ushort*)alloc((size_t)NN * 256 * 2);  // agg output (bf16)
    ushort* vb   = (ushort*)alloc((size_t)NN * 128 * 2);  // v cast bf16
    ushort* xb   = (ushort*)alloc((size_t)NN * 256 * 2);  // x1b/x2b activations bf16

    hipMemsetAsync(cnt, 0, (size_t)NN * 8, stream);  // cnt + cursor

    k_count<<<(NE + 255) / 256, 256, 0, stream>>>(ei, cnt);
    k_dinv<<<(NN + 255) / 256, 256, 0, stream>>>(cnt, dinv);
    k_scan1<<<NB, 1024, 0, stream>>>(cnt, offs, bsum);
    k_scan2<<<1, 64, 0, stream>>>(bsum, boff, offs);
    k_scan3<<<NB, 1024, 0, stream>>>(offs, boff);
    k_fill<<<(NE + 255) / 256, 256, 0, stream>>>(ei, offs, cursor, dinv, csr_src, csr_w);

    // casts (after k_fill: cnt/cursor region is dead)
    k_castW<<<(128 * 128 + 255) / 256, 256, 0, stream>>>(W1, Wt1, 128, 128);
    k_castW<<<(128 * 256 + 255) / 256, 256, 0, stream>>>(W2, Wt2, 128, 256);
    k_castV<<<(NN * 128 / 4 + 255) / 256, 256, 0, stream>>>(v, vb, NN * 128 / 4);

    int aggGrid = (NN + 3) / 4;
    int gr = (NN + 127) / 128;  // 391 row-tiles

    // Layer 1: agg(vb) -> aggA ; GEMM K=128,N=128 -> x1b (bf16)
    k_aggregate<2><<<aggGrid, 256, 0, stream>>>(vb, aggA, offs, csr_src, csr_w, dinv);
    k_gemm5<4, 1, true><<<gr * 1, 256, 0, stream>>>(aggA, Wt1, b1, xb, NN, 128);

    // Layer 2: agg(x1b) -> aggA ; GEMM K=128,N=256 -> x2b (bf16)
    k_aggregate<2><<<aggGrid, 256, 0, stream>>>(xb, aggA, offs, csr_src, csr_w, dinv);
    k_gemm5<4, 2, true><<<gr * 2, 256, 0, stream>>>(aggA, Wt2, b2, xb, NN, 256);

    // Layer 3: agg(x2b) -> aggA ; cast W3 (csr_src now dead) ; GEMM K=256,N=512 -> out
    k_aggregate<4><<<aggGrid, 256, 0, stream>>>(xb, aggA, offs, csr_src, csr_w, dinv);
    k_castW<<<(256 * 512 + 255) / 256, 256, 0, stream>>>(W3, Wt3, 256, 512);
    k_gemm5<8, 4, false><<<gr * 4, 256, 0, stream>>>(aggA, Wt3, b3, out, NN, 512);
}

// Round 10
// 244.548 us; speedup vs baseline: 1.5032x; 1.1333x over previous
//
#include <hip/hip_runtime.h>
#include <hip/hip_bf16.h>
#include <stdint.h>

static constexpr int NN = 50000;   // nodes
static constexpr int NE = 400000;  // edges
static constexpr int NB = (NN + 1023) / 1024;  // 49 scan blocks

typedef __attribute__((ext_vector_type(8))) short bf16x8;
typedef __attribute__((ext_vector_type(4))) float f32x4;

__device__ inline ushort f2bf(float f) {
    __hip_bfloat16 b = __float2bfloat16(f);
    return *reinterpret_cast<ushort*>(&b);
}
__device__ inline float bfu2f(ushort u) {
    unsigned x = (unsigned)u << 16;
    return __builtin_bit_cast(float, x);
}

__device__ __forceinline__ void gload16(const void* g, void* l) {
    __builtin_amdgcn_global_load_lds(
        (const __attribute__((address_space(1))) void*)g,
        (__attribute__((address_space(3))) void*)l, 16, 0, 0);
}

// ---------------- CSR build (edge_index is int32 from harness) ----------------

__global__ void k_count(const int* __restrict__ ei, unsigned* __restrict__ cnt) {
    int e = blockIdx.x * blockDim.x + threadIdx.x;
    if (e < NE) atomicAdd(&cnt[ei[NE + e]], 1u);
}

__global__ void k_dinv(const unsigned* __restrict__ cnt, float* __restrict__ dinv) {
    int i = blockIdx.x * blockDim.x + threadIdx.x;
    if (i < NN) dinv[i] = rsqrtf((float)(cnt[i] + 1u));  // deg includes self-loop
}

// --- hierarchical exclusive scan ---

__global__ __launch_bounds__(1024) void k_scan1(const unsigned* __restrict__ cnt,
                                                unsigned* __restrict__ offs,
                                                unsigned* __restrict__ bsum) {
    __shared__ unsigned sh[1024];
    int i = blockIdx.x * 1024 + (int)threadIdx.x;
    unsigned v = (i < NN) ? cnt[i] : 0u;
    sh[threadIdx.x] = v;
    __syncthreads();
    #pragma unroll
    for (int off = 1; off < 1024; off <<= 1) {
        unsigned add = (threadIdx.x >= (unsigned)off) ? sh[threadIdx.x - off] : 0u;
        __syncthreads();
        sh[threadIdx.x] += add;
        __syncthreads();
    }
    if (i < NN) offs[i] = sh[threadIdx.x] - v;  // block-local exclusive
    if (threadIdx.x == 1023) bsum[blockIdx.x] = sh[1023];
}

__global__ void k_scan2(const unsigned* __restrict__ bsum, unsigned* __restrict__ boff,
                        unsigned* __restrict__ offs) {
    if (threadIdx.x == 0) {
        unsigned acc = 0;
        for (int b = 0; b < NB; ++b) { boff[b] = acc; acc += bsum[b]; }
        offs[NN] = acc;  // == NE
    }
}

__global__ __launch_bounds__(1024) void k_scan3(unsigned* __restrict__ offs,
                                                const unsigned* __restrict__ boff) {
    int i = blockIdx.x * 1024 + (int)threadIdx.x;
    if (i < NN) offs[i] += boff[blockIdx.x];
}

__global__ void k_fill(const int* __restrict__ ei, const unsigned* __restrict__ offs,
                       unsigned* __restrict__ cursor, const float* __restrict__ dinv,
                       unsigned* __restrict__ csr_src, float* __restrict__ csr_w) {
    int e = blockIdx.x * blockDim.x + threadIdx.x;
    if (e < NE) {
        int s = ei[e];
        int d = ei[NE + e];
        unsigned pos = offs[d] + atomicAdd(&cursor[d], 1u);
        csr_src[pos] = (unsigned)s;
        csr_w[pos] = dinv[s] * dinv[d];
    }
}

// -------- Weight cast+transpose: W[K][N] fp32 -> Wt [N][K] bf16 --------

__global__ void k_castW(const float* __restrict__ W, ushort* __restrict__ Wt, int K, int N) {
    int i = blockIdx.x * 256 + (int)threadIdx.x;
    if (i >= K * N) return;
    int k = i / N, n = i - k * N;
    Wt[n * K + k] = f2bf(W[i]);
}

// -------- v fp32 -> bf16 (vectorized) --------

__global__ void k_castV(const float* __restrict__ v, ushort* __restrict__ vb, int n4) {
    int i = blockIdx.x * 256 + (int)threadIdx.x;
    if (i >= n4) return;
    float4 f = *reinterpret_cast<const float4*>(v + (size_t)i * 4);
    *reinterpret_cast<ushort4*>(vb + (size_t)i * 4) =
        make_ushort4(f2bf(f.x), f2bf(f.y), f2bf(f.z), f2bf(f.w));
}

// ------- Aggregation: y = A_hat * x (bf16 in/out), edge loop unrolled x4 -------

template <int VEC>
__global__ __launch_bounds__(256) void k_aggregate(
        const ushort* __restrict__ x, ushort* __restrict__ y,
        const unsigned* __restrict__ offs, const unsigned* __restrict__ csr_src,
        const float* __restrict__ csr_w, const float* __restrict__ dinv) {
    const int F = 64 * VEC;
    int node = blockIdx.x * 4 + ((int)threadIdx.x >> 6);
    int lane = (int)threadIdx.x & 63;
    if (node >= NN) return;

    float di = dinv[node];
    float sw = di * di;
    float acc[VEC];
    const ushort* xs = x + (size_t)node * F + lane * VEC;
    #pragma unroll
    for (int j = 0; j < VEC; ++j) acc[j] = sw * bfu2f(xs[j]);

    auto ld = [&](unsigned s, ushort* u) {
        const ushort* xr = x + (size_t)s * F + lane * VEC;
        if constexpr (VEC == 2)
            *reinterpret_cast<ushort2*>(u) = *reinterpret_cast<const ushort2*>(xr);
        else
            *reinterpret_cast<ushort4*>(u) = *reinterpret_cast<const ushort4*>(xr);
    };

    unsigned beg = offs[node], end = offs[node + 1];
    unsigned idx = beg;
    for (; idx + 3 < end; idx += 4) {
        unsigned s0 = csr_src[idx], s1 = csr_src[idx + 1];
        unsigned s2 = csr_src[idx + 2], s3 = csr_src[idx + 3];
        float w0 = csr_w[idx], w1 = csr_w[idx + 1];
        float w2 = csr_w[idx + 2], w3 = csr_w[idx + 3];
        ushort u0[VEC], u1[VEC], u2[VEC], u3[VEC];
        ld(s0, u0); ld(s1, u1); ld(s2, u2); ld(s3, u3);
        #pragma unroll
        for (int j = 0; j < VEC; ++j) {
            acc[j] = fmaf(w0, bfu2f(u0[j]), acc[j]);
            acc[j] = fmaf(w1, bfu2f(u1[j]), acc[j]);
            acc[j] = fmaf(w2, bfu2f(u2[j]), acc[j]);
            acc[j] = fmaf(w3, bfu2f(u3[j]), acc[j]);
        }
    }
    for (; idx < end; ++idx) {
        unsigned s0 = csr_src[idx];
        float w0 = csr_w[idx];
        ushort u0[VEC];
        ld(s0, u0);
        #pragma unroll
        for (int j = 0; j < VEC; ++j) acc[j] = fmaf(w0, bfu2f(u0[j]), acc[j]);
    }

    size_t ybase = (size_t)node * F + lane * VEC;
    ushort h[VEC];
    #pragma unroll
    for (int j = 0; j < VEC; ++j) h[j] = f2bf(acc[j]);
    if constexpr (VEC == 2) {
        *reinterpret_cast<ushort2*>(y + ybase) = make_ushort2(h[0], h[1]);
    } else {
        *reinterpret_cast<ushort4*>(y + ybase) = make_ushort4(h[0], h[1], h[2], h[3]);
    }
}

// ------- GEMM: bf16 A, B-in-LDS K-chunked, 64x64 wave tiles, 3-stage A pipeline,
//         per-mi LDS-transpose epilogue (stride 68 >= 64: no row overlap) -------

template <int NT, int SC, bool OUTB>  // K = NT*32 ; SC = N/128
__global__ __launch_bounds__(256, 3) void k_gemm6(
        const ushort* __restrict__ Ah, const ushort* __restrict__ Wt,
        const float* __restrict__ bias, void* __restrict__ Cout, int M, int N) {
    constexpr int K = NT * 32;
    constexpr int CHT = (NT > 4) ? 4 : NT;   // K-steps per staged chunk
    constexpr int NCH = NT / CHT;            // chunks
    // union: B staging (32KB) | epilogue transpose (4 waves x 16 rows x 68 stride = 17.4KB)
    __shared__ __align__(16) float smem[8192];  // 32KB
    short* sB = (short*)smem;

    // bijective XCD swizzle
    int nwg = (int)gridDim.x;
    int bid = (int)blockIdx.x;
    int q = nwg >> 3, r = nwg & 7;
    int xcd = bid & 7, seq = bid >> 3;
    int swz = (xcd < r ? xcd * (q + 1) : r * (q + 1) + (xcd - r) * q) + seq;
    int bx = swz % SC, by = swz / SC;
    int col0 = bx * 128, row0 = by * 128;

    int tid = (int)threadIdx.x;
    int w = tid >> 6, lane = tid & 63;
    int wr = w >> 1, wc = w & 1;
    int r16 = lane & 15, kg = lane >> 4;

    size_t aoff[4];
    #pragma unroll
    for (int mi = 0; mi < 4; ++mi) {
        int row = row0 + wr * 64 + mi * 16 + r16;
        if (row >= M) row = M - 1;  // clamp reads; stores guarded
        aoff[mi] = (size_t)row * K + kg * 8;
    }

    f32x4 acc[4][4] = {};
    bf16x8 ah[3][4];  // 3-stage A pipeline (compile-time indexed: loops fully unrolled)

    #pragma unroll
    for (int mi = 0; mi < 4; ++mi)
        ah[0][mi] = *reinterpret_cast<const bf16x8*>(Ah + aoff[mi]);
    if constexpr (NT > 1) {
        #pragma unroll
        for (int mi = 0; mi < 4; ++mi)
            ah[1][mi] = *reinterpret_cast<const bf16x8*>(Ah + aoff[mi] + 32);
    }

    #pragma unroll
    for (int kc = 0; kc < NCH; ++kc) {
        if (kc) __syncthreads();  // prev chunk fully consumed before overwrite
        #pragma unroll
        for (int i = 0; i < CHT * 2; ++i) {
            int c = i * 256 + tid;
            int tl = c >> 9, ckg = (c >> 7) & 3, n = c & 127;
            gload16(Wt + (size_t)(col0 + n) * K + (kc * CHT + tl) * 32 + ckg * 8,
                    sB + c * 8);
        }
        __syncthreads();

        #pragma unroll
        for (int t = 0; t < CHT; ++t) {
            const int tg = kc * CHT + t;           // compile-time
            const int cur = tg % 3;
            if (tg + 2 < NT) {
                const int nxt = (tg + 2) % 3;
                #pragma unroll
                for (int mi = 0; mi < 4; ++mi)
                    ah[nxt][mi] = *reinterpret_cast<const bf16x8*>(Ah + aoff[mi] + (tg + 2) * 32);
            }
            bf16x8 bb[4];
            #pragma unroll
            for (int ni = 0; ni < 4; ++ni)
                bb[ni] = *reinterpret_cast<const bf16x8*>(
                    sB + ((t * 4 + kg) * 128 + wc * 64 + ni * 16 + r16) * 8);
            #pragma unroll
            for (int ni = 0; ni < 4; ++ni)
                #pragma unroll
                for (int mi = 0; mi < 4; ++mi)
                    acc[mi][ni] = __builtin_amdgcn_mfma_f32_16x16x32_bf16(ah[cur][mi], bb[ni], acc[mi][ni], 0, 0, 0);
        }
    }

    // ---- per-mi LDS-transpose epilogue: full-line coalesced stores ----
    __syncthreads();  // all waves done reading sB before overwrite
    float* ep = smem + w * (16 * 68);  // per-wave private 16x68 slice
    int crow0 = (lane >> 4) * 4;       // acc row group within 16
    int ccol = lane & 15;              // acc col within 16
    int rb = row0 + wr * 64;
    int cb = col0 + wc * 64;
    int rl0 = lane >> 4;               // 0..3: row within 4-row store pass
    int cl = (lane & 15) * 4;          // float4 col offset
    float4 bv = *reinterpret_cast<const float4*>(&bias[cb + cl]);
    #pragma unroll
    for (int mi = 0; mi < 4; ++mi) {
        // scatter this 16-row group into LDS (2-way banks = free)
        #pragma unroll
        for (int ni = 0; ni < 4; ++ni)
            #pragma unroll
            for (int j = 0; j < 4; ++j)
                ep[(crow0 + j) * 68 + ni * 16 + ccol] = acc[mi][ni][j];
        // read back row-major (same wave, in-order DS pipe) and store 256B/instr
        #pragma unroll
        for (int s = 0; s < 4; ++s) {
            int rl = s * 4 + rl0;
            int row = rb + mi * 16 + rl;
            if (row < M) {
                float4 vv = *reinterpret_cast<const float4*>(ep + rl * 68 + cl);
                float4 o;
                o.x = fmaxf(vv.x + bv.x, 0.f);
                o.y = fmaxf(vv.y + bv.y, 0.f);
                o.z = fmaxf(vv.z + bv.z, 0.f);
                o.w = fmaxf(vv.w + bv.w, 0.f);
                if constexpr (OUTB) {
                    *reinterpret_cast<ushort4*>((ushort*)Cout + (size_t)row * N + cb + cl) =
                        make_ushort4(f2bf(o.x), f2bf(o.y), f2bf(o.z), f2bf(o.w));
                } else {
                    *reinterpret_cast<float4*>((float*)Cout + (size_t)row * N + cb + cl) = o;
                }
            }
        }
        // next mi reuses the slice; within-wave WAR handled by in-order DS + lgkmcnt
    }
}

// ---------------- launch ----------------

extern "C" void kernel_launch(void* const* d_in, const int* in_sizes, int n_in,
                              void* d_out, int out_size, void* d_ws, size_t ws_size,
                              hipStream_t stream) {
    const float* v  = (const float*)d_in[0];
    const int* ei   = (const int*)d_in[1];
    const float* W1 = (const float*)d_in[2];
    const float* b1 = (const float*)d_in[3];
    const float* W2 = (const float*)d_in[4];
    const float* b2 = (const float*)d_in[5];
    const float* W3 = (const float*)d_in[6];
    const float* b3 = (const float*)d_in[7];
    float* out = (float*)d_out;

    char* ws = (char*)d_ws;
    size_t off = 0;
    auto alloc = [&](size_t bytes) {
        void* p = ws + off;
        off = (off + bytes + 255) & ~(size_t)255;
        return p;
    };
    // cnt+cursor at front; dead after k_fill -> overlaid by Wt1/Wt2 (96KB <= 400KB).
    unsigned* cnt    = (unsigned*)(ws + 0);
    unsigned* cursor = (unsigned*)(ws + (size_t)NN * 4);
    ushort* Wt1 = (ushort*)ws;               // [128][128] = 32KB
    ushort* Wt2 = Wt1 + 128 * 128;           // [256][128] = 64KB
    off = ((size_t)NN * 8 + 255) & ~(size_t)255;
    unsigned* offs    = (unsigned*)alloc((size_t)(NN + 1) * 4);
    float*    dinv    = (float*)alloc((size_t)NN * 4);
    unsigned* bsum    = (unsigned*)alloc((size_t)NB * 4);
    unsigned* boff    = (unsigned*)alloc((size_t)NB * 4);
    unsigned* csr_src = (unsigned*)alloc((size_t)NE * 4);
    float*    csr_w   = (float*)alloc((size_t)NE * 4);
    // csr_src dead after agg3 -> overlaid by Wt3 [512][256] = 256KB <= 1.6MB.
    ushort* Wt3 = (ushort*)csr_src;
    ushort* aggA = (ushort*)alloc((size_t)NN * 256 * 2);  // agg output (bf16)
    ushort* vb   = (ushort*)alloc((size_t)NN * 128 * 2);  // v cast bf16
    ushort* xb   = (ushort*)alloc((size_t)NN * 256 * 2);  // x1b/x2b activations bf16

    hipMemsetAsync(cnt, 0, (size_t)NN * 8, stream);  // cnt + cursor

    k_count<<<(NE + 255) / 256, 256, 0, stream>>>(ei, cnt);
    k_dinv<<<(NN + 255) / 256, 256, 0, stream>>>(cnt, dinv);
    k_scan1<<<NB, 1024, 0, stream>>>(cnt, offs, bsum);
    k_scan2<<<1, 64, 0, stream>>>(bsum, boff, offs);
    k_scan3<<<NB, 1024, 0, stream>>>(offs, boff);
    k_fill<<<(NE + 255) / 256, 256, 0, stream>>>(ei, offs, cursor, dinv, csr_src, csr_w);

    // casts (after k_fill: cnt/cursor region is dead)
    k_castW<<<(128 * 128 + 255) / 256, 256, 0, stream>>>(W1, Wt1, 128, 128);
    k_castW<<<(128 * 256 + 255) / 256, 256, 0, stream>>>(W2, Wt2, 128, 256);
    k_castV<<<(NN * 128 / 4 + 255) / 256, 256, 0, stream>>>(v, vb, NN * 128 / 4);

    int aggGrid = (NN + 3) / 4;
    int gr = (NN + 127) / 128;  // 391 row-tiles

    // Layer 1: agg(vb) -> aggA ; GEMM K=128,N=128 -> x1b (bf16)
    k_aggregate<2><<<aggGrid, 256, 0, stream>>>(vb, aggA, offs, csr_src, csr_w, dinv);
    k_gemm6<4, 1, true><<<gr * 1, 256, 0, stream>>>(aggA, Wt1, b1, xb, NN, 128);

    // Layer 2: agg(x1b) -> aggA ; GEMM K=128,N=256 -> x2b (bf16)
    k_aggregate<2><<<aggGrid, 256, 0, stream>>>(xb, aggA, offs, csr_src, csr_w, dinv);
    k_gemm6<4, 2, true><<<gr * 2, 256, 0, stream>>>(aggA, Wt2, b2, xb, NN, 256);

    // Layer 3: agg(x2b) -> aggA ; cast W3 (csr_src now dead) ; GEMM K=256,N=512 -> out
    k_aggregate<4><<<aggGrid, 256, 0, stream>>>(xb, aggA, offs, csr_src, csr_w, dinv);
    k_castW<<<(256 * 512 + 255) / 256, 256, 0, stream>>>(W3, Wt3, 256, 512);
    k_gemm6<8, 4, false><<<gr * 4, 256, 0, stream>>>(aggA, Wt3, b3, out, NN, 512);
}

// Round 12
// 238.648 us; speedup vs baseline: 1.5404x; 1.0247x over previous
//
#include <hip/hip_runtime.h>
#include <hip/hip_bf16.h>
#include <stdint.h>

static constexpr int NN = 50000;   // nodes
static constexpr int NE = 400000;  // edges
static constexpr int NB = (NN + 1023) / 1024;  // 49 scan blocks

typedef __attribute__((ext_vector_type(8))) short bf16x8;
typedef __attribute__((ext_vector_type(8))) unsigned short u16x8;
typedef __attribute__((ext_vector_type(4))) float f32x4;

__device__ inline ushort f2bf(float f) {
    __hip_bfloat16 b = __float2bfloat16(f);
    return *reinterpret_cast<ushort*>(&b);
}
__device__ inline float bfu2f(ushort u) {
    unsigned x = (unsigned)u << 16;
    return __builtin_bit_cast(float, x);
}

__device__ __forceinline__ void gload16(const void* g, void* l) {
    __builtin_amdgcn_global_load_lds(
        (const __attribute__((address_space(1))) void*)g,
        (__attribute__((address_space(3))) void*)l, 16, 0, 0);
}

// ---------------- CSR build (edge_index is int32 from harness) ----------------

__global__ void k_count(const int* __restrict__ ei, unsigned* __restrict__ cnt) {
    int e = blockIdx.x * blockDim.x + threadIdx.x;
    if (e < NE) atomicAdd(&cnt[ei[NE + e]], 1u);
}

__global__ void k_dinv(const unsigned* __restrict__ cnt, float* __restrict__ dinv) {
    int i = blockIdx.x * blockDim.x + threadIdx.x;
    if (i < NN) dinv[i] = rsqrtf((float)(cnt[i] + 1u));  // deg includes self-loop
}

// --- hierarchical exclusive scan ---

__global__ __launch_bounds__(1024) void k_scan1(const unsigned* __restrict__ cnt,
                                                unsigned* __restrict__ offs,
                                                unsigned* __restrict__ bsum) {
    __shared__ unsigned sh[1024];
    int i = blockIdx.x * 1024 + (int)threadIdx.x;
    unsigned v = (i < NN) ? cnt[i] : 0u;
    sh[threadIdx.x] = v;
    __syncthreads();
    #pragma unroll
    for (int off = 1; off < 1024; off <<= 1) {
        unsigned add = (threadIdx.x >= (unsigned)off) ? sh[threadIdx.x - off] : 0u;
        __syncthreads();
        sh[threadIdx.x] += add;
        __syncthreads();
    }
    if (i < NN) offs[i] = sh[threadIdx.x] - v;  // block-local exclusive
    if (threadIdx.x == 1023) bsum[blockIdx.x] = sh[1023];
}

__global__ void k_scan2(const unsigned* __restrict__ bsum, unsigned* __restrict__ boff,
                        unsigned* __restrict__ offs) {
    if (threadIdx.x == 0) {
        unsigned acc = 0;
        for (int b = 0; b < NB; ++b) { boff[b] = acc; acc += bsum[b]; }
        offs[NN] = acc;  // == NE
    }
}

__global__ __launch_bounds__(1024) void k_scan3(unsigned* __restrict__ offs,
                                                const unsigned* __restrict__ boff) {
    int i = blockIdx.x * 1024 + (int)threadIdx.x;
    if (i < NN) offs[i] += boff[blockIdx.x];
}

__global__ void k_fill(const int* __restrict__ ei, const unsigned* __restrict__ offs,
                       unsigned* __restrict__ cursor, const float* __restrict__ dinv,
                       unsigned* __restrict__ csr_src, float* __restrict__ csr_w) {
    int e = blockIdx.x * blockDim.x + threadIdx.x;
    if (e < NE) {
        int s = ei[e];
        int d = ei[NE + e];
        unsigned pos = offs[d] + atomicAdd(&cursor[d], 1u);
        csr_src[pos] = (unsigned)s;
        csr_w[pos] = dinv[s] * dinv[d];
    }
}

// -------- Weight cast+transpose: W[K][N] fp32 -> Wt [N][K] bf16 --------

__global__ void k_castW(const float* __restrict__ W, ushort* __restrict__ Wt, int K, int N) {
    int i = blockIdx.x * 256 + (int)threadIdx.x;
    if (i >= K * N) return;
    int k = i / N, n = i - k * N;
    Wt[n * K + k] = f2bf(W[i]);
}

// -------- v fp32 -> bf16 (vectorized) --------

__global__ void k_castV(const float* __restrict__ v, ushort* __restrict__ vb, int n4) {
    int i = blockIdx.x * 256 + (int)threadIdx.x;
    if (i >= n4) return;
    float4 f = *reinterpret_cast<const float4*>(v + (size_t)i * 4);
    *reinterpret_cast<ushort4*>(vb + (size_t)i * 4) =
        make_ushort4(f2bf(f.x), f2bf(f.y), f2bf(f.z), f2bf(f.w));
}

// ------- Aggregation: y = A_hat * x (bf16 in/out), split-wave: 2 edges in
//         parallel (32 lanes each, wide per-lane loads), unroll x2 -------

template <int VEC>  // F = 64*VEC ; per-lane PL = 2*VEC bf16 (32 lanes cover a row)
__global__ __launch_bounds__(256) void k_aggregate(
        const ushort* __restrict__ x, ushort* __restrict__ y,
        const unsigned* __restrict__ offs, const unsigned* __restrict__ csr_src,
        const float* __restrict__ csr_w, const float* __restrict__ dinv) {
    const int F = 64 * VEC;
    const int PL = 2 * VEC;  // bf16 per lane: 4 (8B) or 8 (16B)
    int node = blockIdx.x * 4 + ((int)threadIdx.x >> 6);
    int lane = (int)threadIdx.x & 63;
    if (node >= NN) return;
    int h = lane >> 5;       // which edge of the pair this half-wave handles
    int sl = lane & 31;      // slice within row

    auto ld = [&](const ushort* p, ushort* u) {
        if constexpr (VEC == 2)
            *reinterpret_cast<ushort4*>(u) = *reinterpret_cast<const ushort4*>(p);
        else
            *reinterpret_cast<u16x8*>(u) = *reinterpret_cast<const u16x8*>(p);
    };

    float di = dinv[node];
    float sw = (h == 0) ? di * di : 0.f;  // self term counted once
    float acc[PL];
    {
        ushort u[PL];
        ld(x + (size_t)node * F + sl * PL, u);
        #pragma unroll
        for (int j = 0; j < PL; ++j) acc[j] = sw * bfu2f(u[j]);
    }

    unsigned beg = offs[node], end = offs[node + 1];
    unsigned e = beg + h;
    for (; e + 2 < end; e += 4) {  // two pair-steps: 4 edges in flight wave-wide
        unsigned s0 = csr_src[e], s1 = csr_src[e + 2];
        float w0 = csr_w[e], w1 = csr_w[e + 2];
        ushort u0[PL], u1[PL];
        ld(x + (size_t)s0 * F + sl * PL, u0);
        ld(x + (size_t)s1 * F + sl * PL, u1);
        #pragma unroll
        for (int j = 0; j < PL; ++j) {
            acc[j] = fmaf(w0, bfu2f(u0[j]), acc[j]);
            acc[j] = fmaf(w1, bfu2f(u1[j]), acc[j]);
        }
    }
    if (e < end) {
        unsigned s0 = csr_src[e];
        float w0 = csr_w[e];
        ushort u0[PL];
        ld(x + (size_t)s0 * F + sl * PL, u0);
        #pragma unroll
        for (int j = 0; j < PL; ++j) acc[j] = fmaf(w0, bfu2f(u0[j]), acc[j]);
    }

    // combine the two halves (lane l <-> l^32)
    #pragma unroll
    for (int j = 0; j < PL; ++j) acc[j] += __shfl_xor(acc[j], 32);

    if (h == 0) {
        ushort hh[PL];
        #pragma unroll
        for (int j = 0; j < PL; ++j) hh[j] = f2bf(acc[j]);
        ushort* yp = y + (size_t)node * F + sl * PL;
        if constexpr (VEC == 2)
            *reinterpret_cast<ushort4*>(yp) = *reinterpret_cast<ushort4*>(hh);
        else
            *reinterpret_cast<u16x8*>(yp) = *reinterpret_cast<u16x8*>(hh);
    }
}

// ------- GEMM: bf16 A, B-in-LDS (CHT=2 -> 16KB chunks), 64x64 wave tiles,
//         3-stage A pipeline, per-mi LDS-transpose epilogue, NT stores for fp32 out

template <int NT, int SC, bool OUTB>  // K = NT*32 ; SC = N/128
__global__ __launch_bounds__(256, 4) void k_gemm7(
        const ushort* __restrict__ Ah, const ushort* __restrict__ Wt,
        const float* __restrict__ bias, void* __restrict__ Cout, int M, int N) {
    constexpr int K = NT * 32;
    constexpr int CHT = (NT > 2) ? 2 : NT;   // K-steps per staged chunk (16KB)
    constexpr int NCH = NT / CHT;            // chunks
    // union: B staging (CHT*8KB = 16KB) | epilogue transpose (4 x 16 x 68 f32 = 17.4KB)
    __shared__ __align__(16) float smem[4352];
    short* sB = (short*)smem;

    // bijective XCD swizzle
    int nwg = (int)gridDim.x;
    int bid = (int)blockIdx.x;
    int q = nwg >> 3, r = nwg & 7;
    int xcd = bid & 7, seq = bid >> 3;
    int swz = (xcd < r ? xcd * (q + 1) : r * (q + 1) + (xcd - r) * q) + seq;
    int bx = swz % SC, by = swz / SC;
    int col0 = bx * 128, row0 = by * 128;

    int tid = (int)threadIdx.x;
    int w = tid >> 6, lane = tid & 63;
    int wr = w >> 1, wc = w & 1;
    int r16 = lane & 15, kg = lane >> 4;

    size_t aoff[4];
    #pragma unroll
    for (int mi = 0; mi < 4; ++mi) {
        int row = row0 + wr * 64 + mi * 16 + r16;
        if (row >= M) row = M - 1;  // clamp reads; stores guarded
        aoff[mi] = (size_t)row * K + kg * 8;
    }

    f32x4 acc[4][4] = {};
    bf16x8 ah[3][4];  // 3-stage A pipeline (compile-time indexed: loops fully unrolled)

    #pragma unroll
    for (int mi = 0; mi < 4; ++mi)
        ah[0][mi] = *reinterpret_cast<const bf16x8*>(Ah + aoff[mi]);
    if constexpr (NT > 1) {
        #pragma unroll
        for (int mi = 0; mi < 4; ++mi)
            ah[1][mi] = *reinterpret_cast<const bf16x8*>(Ah + aoff[mi] + 32);
    }

    #pragma unroll
    for (int kc = 0; kc < NCH; ++kc) {
        if (kc) __syncthreads();  // prev chunk fully consumed before overwrite
        #pragma unroll
        for (int i = 0; i < CHT * 2; ++i) {
            int c = i * 256 + tid;                     // 0 .. CHT*512-1
            int tl = c >> 9, ckg = (c >> 7) & 3, n = c & 127;
            gload16(Wt + (size_t)(col0 + n) * K + (kc * CHT + tl) * 32 + ckg * 8,
                    sB + c * 8);
        }
        __syncthreads();

        #pragma unroll
        for (int t = 0; t < CHT; ++t) {
            const int tg = kc * CHT + t;           // compile-time
            const int cur = tg % 3;
            if (tg + 2 < NT) {
                const int nxt = (tg + 2) % 3;
                #pragma unroll
                for (int mi = 0; mi < 4; ++mi)
                    ah[nxt][mi] = *reinterpret_cast<const bf16x8*>(Ah + aoff[mi] + (tg + 2) * 32);
            }
            bf16x8 bb[4];
            #pragma unroll
            for (int ni = 0; ni < 4; ++ni)
                bb[ni] = *reinterpret_cast<const bf16x8*>(
                    sB + ((t * 4 + kg) * 128 + wc * 64 + ni * 16 + r16) * 8);
            #pragma unroll
            for (int ni = 0; ni < 4; ++ni)
                #pragma unroll
                for (int mi = 0; mi < 4; ++mi)
                    acc[mi][ni] = __builtin_amdgcn_mfma_f32_16x16x32_bf16(ah[cur][mi], bb[ni], acc[mi][ni], 0, 0, 0);
        }
    }

    // ---- per-mi LDS-transpose epilogue: full-line coalesced stores ----
    __syncthreads();  // all waves done reading sB before overwrite
    float* ep = smem + w * (16 * 68);  // per-wave private 16x68 slice
    int crow0 = (lane >> 4) * 4;
    int ccol = lane & 15;
    int rb = row0 + wr * 64;
    int cb = col0 + wc * 64;
    int rl0 = lane >> 4;
    int cl = (lane & 15) * 4;
    float4 bv = *reinterpret_cast<const float4*>(&bias[cb + cl]);
    #pragma unroll
    for (int mi = 0; mi < 4; ++mi) {
        #pragma unroll
        for (int ni = 0; ni < 4; ++ni)
            #pragma unroll
            for (int j = 0; j < 4; ++j)
                ep[(crow0 + j) * 68 + ni * 16 + ccol] = acc[mi][ni][j];
        #pragma unroll
        for (int s = 0; s < 4; ++s) {
            int rl = s * 4 + rl0;
            int row = rb + mi * 16 + rl;
            if (row < M) {
                float4 vv = *reinterpret_cast<const float4*>(ep + rl * 68 + cl);
                float4 o;
                o.x = fmaxf(vv.x + bv.x, 0.f);
                o.y = fmaxf(vv.y + bv.y, 0.f);
                o.z = fmaxf(vv.z + bv.z, 0.f);
                o.w = fmaxf(vv.w + bv.w, 0.f);
                if constexpr (OUTB) {
                    *reinterpret_cast<ushort4*>((ushort*)Cout + (size_t)row * N + cb + cl) =
                        make_ushort4(f2bf(o.x), f2bf(o.y), f2bf(o.z), f2bf(o.w));
                } else {
                    // final output: never re-read -> nontemporal (ext-vector type, not HIP float4)
                    f32x4 ov = {o.x, o.y, o.z, o.w};
                    __builtin_nontemporal_store(
                        ov, reinterpret_cast<f32x4*>((float*)Cout + (size_t)row * N + cb + cl));
                }
            }
        }
    }
}

// ---------------- launch ----------------

extern "C" void kernel_launch(void* const* d_in, const int* in_sizes, int n_in,
                              void* d_out, int out_size, void* d_ws, size_t ws_size,
                              hipStream_t stream) {
    const float* v  = (const float*)d_in[0];
    const int* ei   = (const int*)d_in[1];
    const float* W1 = (const float*)d_in[2];
    const float* b1 = (const float*)d_in[3];
    const float* W2 = (const float*)d_in[4];
    const float* b2 = (const float*)d_in[5];
    const float* W3 = (const float*)d_in[6];
    const float* b3 = (const float*)d_in[7];
    float* out = (float*)d_out;

    char* ws = (char*)d_ws;
    size_t off = 0;
    auto alloc = [&](size_t bytes) {
        void* p = ws + off;
        off = (off + bytes + 255) & ~(size_t)255;
        return p;
    };
    // cnt+cursor at front; dead after k_fill -> overlaid by Wt1/Wt2 (96KB <= 400KB).
    unsigned* cnt    = (unsigned*)(ws + 0);
    unsigned* cursor = (unsigned*)(ws + (size_t)NN * 4);
    ushort* Wt1 = (ushort*)ws;               // [128][128] = 32KB
    ushort* Wt2 = Wt1 + 128 * 128;           // [256][128] = 64KB
    off = ((size_t)NN * 8 + 255) & ~(size_t)255;
    unsigned* offs    = (unsigned*)alloc((size_t)(NN + 1) * 4);
    float*    dinv    = (float*)alloc((size_t)NN * 4);
    unsigned* bsum    = (unsigned*)alloc((size_t)NB * 4);
    unsigned* boff    = (unsigned*)alloc((size_t)NB * 4);
    unsigned* csr_src = (unsigned*)alloc((size_t)NE * 4);
    float*    csr_w   = (float*)alloc((size_t)NE * 4);
    // csr_src dead after agg3 -> overlaid by Wt3 [512][256] = 256KB <= 1.6MB.
    ushort* Wt3 = (ushort*)csr_src;
    ushort* aggA = (ushort*)alloc((size_t)NN * 256 * 2);  // agg output (bf16)
    ushort* vb   = (ushort*)alloc((size_t)NN * 128 * 2);  // v cast bf16
    ushort* xb   = (ushort*)alloc((size_t)NN * 256 * 2);  // x1b/x2b activations bf16

    hipMemsetAsync(cnt, 0, (size_t)NN * 8, stream);  // cnt + cursor

    k_count<<<(NE + 255) / 256, 256, 0, stream>>>(ei, cnt);
    k_dinv<<<(NN + 255) / 256, 256, 0, stream>>>(cnt, dinv);
    k_scan1<<<NB, 1024, 0, stream>>>(cnt, offs, bsum);
    k_scan2<<<1, 64, 0, stream>>>(bsum, boff, offs);
    k_scan3<<<NB, 1024, 0, stream>>>(offs, boff);
    k_fill<<<(NE + 255) / 256, 256, 0, stream>>>(ei, offs, cursor, dinv, csr_src, csr_w);

    // casts (after k_fill: cnt/cursor region is dead)
    k_castW<<<(128 * 128 + 255) / 256, 256, 0, stream>>>(W1, Wt1, 128, 128);
    k_castW<<<(128 * 256 + 255) / 256, 256, 0, stream>>>(W2, Wt2, 128, 256);
    k_castV<<<(NN * 128 / 4 + 255) / 256, 256, 0, stream>>>(v, vb, NN * 128 / 4);

    int aggGrid = (NN + 3) / 4;
    int gr = (NN + 127) / 128;  // 391 row-tiles

    // Layer 1: agg(vb) -> aggA ; GEMM K=128,N=128 -> x1b (bf16)
    k_aggregate<2><<<aggGrid, 256, 0, stream>>>(vb, aggA, offs, csr_src, csr_w, dinv);
    k_gemm7<4, 1, true><<<gr * 1, 256, 0, stream>>>(aggA, Wt1, b1, xb, NN, 128);

    // Layer 2: agg(x1b) -> aggA ; GEMM K=128,N=256 -> x2b (bf16)
    k_aggregate<2><<<aggGrid, 256, 0, stream>>>(xb, aggA, offs, csr_src, csr_w, dinv);
    k_gemm7<4, 2, true><<<gr * 2, 256, 0, stream>>>(aggA, Wt2, b2, xb, NN, 256);

    // Layer 3: agg(x2b) -> aggA ; cast W3 (csr_src now dead) ; GEMM K=256,N=512 -> out
    k_aggregate<4><<<aggGrid, 256, 0, stream>>>(xb, aggA, offs, csr_src, csr_w, dinv);
    k_castW<<<(256 * 512 + 255) / 256, 256, 0, stream>>>(W3, Wt3, 256, 512);
    k_gemm7<8, 4, false><<<gr * 4, 256, 0, stream>>>(aggA, Wt3, b3, out, NN, 512);
}

// Round 14
// 233.030 us; speedup vs baseline: 1.5775x; 1.0241x over previous
//
#include <hip/hip_runtime.h>
#include <hip/hip_bf16.h>
#include <stdint.h>

static constexpr int NN = 50000;   // nodes
static constexpr int NE = 400000;  // edges
static constexpr int NB = (NN + 1023) / 1024;  // 49 scan blocks

typedef __attribute__((ext_vector_type(8))) short bf16x8;
typedef __attribute__((ext_vector_type(8))) unsigned short u16x8;
typedef __attribute__((ext_vector_type(4))) float f32x4;

__device__ inline ushort f2bf(float f) {
    __hip_bfloat16 b = __float2bfloat16(f);
    return *reinterpret_cast<ushort*>(&b);
}
__device__ inline float bfu2f(ushort u) {
    unsigned x = (unsigned)u << 16;
    return __builtin_bit_cast(float, x);
}

__device__ __forceinline__ void gload16(const void* g, void* l) {
    __builtin_amdgcn_global_load_lds(
        (const __attribute__((address_space(1))) void*)g,
        (__attribute__((address_space(3))) void*)l, 16, 0, 0);
}

// ---------------- CSR build (edge_index is int32 from harness) ----------------

__global__ void k_count(const int* __restrict__ ei, unsigned* __restrict__ cnt) {
    int e = blockIdx.x * blockDim.x + threadIdx.x;
    if (e < NE) atomicAdd(&cnt[ei[NE + e]], 1u);
}

__global__ void k_dinv(const unsigned* __restrict__ cnt, float* __restrict__ dinv) {
    int i = blockIdx.x * blockDim.x + threadIdx.x;
    if (i < NN) dinv[i] = rsqrtf((float)(cnt[i] + 1u));  // deg includes self-loop
}

// --- hierarchical exclusive scan ---

__global__ __launch_bounds__(1024) void k_scan1(const unsigned* __restrict__ cnt,
                                                unsigned* __restrict__ offs,
                                                unsigned* __restrict__ bsum) {
    __shared__ unsigned sh[1024];
    int i = blockIdx.x * 1024 + (int)threadIdx.x;
    unsigned v = (i < NN) ? cnt[i] : 0u;
    sh[threadIdx.x] = v;
    __syncthreads();
    #pragma unroll
    for (int off = 1; off < 1024; off <<= 1) {
        unsigned add = (threadIdx.x >= (unsigned)off) ? sh[threadIdx.x - off] : 0u;
        __syncthreads();
        sh[threadIdx.x] += add;
        __syncthreads();
    }
    if (i < NN) offs[i] = sh[threadIdx.x] - v;  // block-local exclusive
    if (threadIdx.x == 1023) bsum[blockIdx.x] = sh[1023];
}

__global__ void k_scan2(const unsigned* __restrict__ bsum, unsigned* __restrict__ boff,
                        unsigned* __restrict__ offs) {
    if (threadIdx.x == 0) {
        unsigned acc = 0;
        for (int b = 0; b < NB; ++b) { boff[b] = acc; acc += bsum[b]; }
        offs[NN] = acc;  // == NE
    }
}

__global__ __launch_bounds__(1024) void k_scan3(unsigned* __restrict__ offs,
                                                const unsigned* __restrict__ boff) {
    int i = blockIdx.x * 1024 + (int)threadIdx.x;
    if (i < NN) offs[i] += boff[blockIdx.x];
}

__global__ void k_fill(const int* __restrict__ ei, const unsigned* __restrict__ offs,
                       unsigned* __restrict__ cursor, const float* __restrict__ dinv,
                       unsigned* __restrict__ csr_src, float* __restrict__ csr_w) {
    int e = blockIdx.x * blockDim.x + threadIdx.x;
    if (e < NE) {
        int s = ei[e];
        int d = ei[NE + e];
        unsigned pos = offs[d] + atomicAdd(&cursor[d], 1u);
        csr_src[pos] = (unsigned)s;
        csr_w[pos] = dinv[s] * dinv[d];
    }
}

// -------- Weight cast+transpose: W[K][N] fp32 -> Wt [N][K] bf16 --------

__global__ void k_castW(const float* __restrict__ W, ushort* __restrict__ Wt, int K, int N) {
    int i = blockIdx.x * 256 + (int)threadIdx.x;
    if (i >= K * N) return;
    int k = i / N, n = i - k * N;
    Wt[n * K + k] = f2bf(W[i]);
}

// -------- v fp32 -> bf16 (vectorized) --------

__global__ void k_castV(const float* __restrict__ v, ushort* __restrict__ vb, int n4) {
    int i = blockIdx.x * 256 + (int)threadIdx.x;
    if (i >= n4) return;
    float4 f = *reinterpret_cast<const float4*>(v + (size_t)i * 4);
    *reinterpret_cast<ushort4*>(vb + (size_t)i * 4) =
        make_ushort4(f2bf(f.x), f2bf(f.y), f2bf(f.z), f2bf(f.w));
}

// ------- Aggregation: y = A_hat * x (bf16 in/out), 8 gathers in flight/wave -------
// LPR lanes (16B each) cover one row; NEP = 64/LPR edges in parallel; unroll U = 8/NEP.

template <int VEC>  // F = 64*VEC
__global__ __launch_bounds__(256) void k_aggregate(
        const ushort* __restrict__ x, ushort* __restrict__ y,
        const unsigned* __restrict__ offs, const unsigned* __restrict__ csr_src,
        const float* __restrict__ csr_w, const float* __restrict__ dinv) {
    const int F = 64 * VEC;
    constexpr int LPR = (VEC == 2) ? 16 : 32;  // lanes per row (16B/lane)
    constexpr int NEP = 64 / LPR;              // parallel edge slots: 4 or 2
    constexpr int U = 8 / NEP;                 // per-slot unroll: 2 or 4
    int node = blockIdx.x * 4 + ((int)threadIdx.x >> 6);
    int lane = (int)threadIdx.x & 63;
    if (node >= NN) return;
    int h = lane / LPR;   // edge slot
    int sl = lane % LPR;  // 16B slice within row

    float di = dinv[node];
    float sw = (h == 0) ? di * di : 0.f;  // self term counted once
    float acc[8];
    {
        u16x8 u = *reinterpret_cast<const u16x8*>(x + (size_t)node * F + sl * 8);
        #pragma unroll
        for (int j = 0; j < 8; ++j) acc[j] = sw * bfu2f(u[j]);
    }

    unsigned beg = offs[node], end = offs[node + 1];
    unsigned e = beg + h;
    for (; e + NEP * (U - 1) < end; e += NEP * U) {
        unsigned s[U]; float w[U]; u16x8 u[U];
        #pragma unroll
        for (int k = 0; k < U; ++k) { s[k] = csr_src[e + NEP * k]; w[k] = csr_w[e + NEP * k]; }
        #pragma unroll
        for (int k = 0; k < U; ++k)
            u[k] = *reinterpret_cast<const u16x8*>(x + (size_t)s[k] * F + sl * 8);
        #pragma unroll
        for (int k = 0; k < U; ++k)
            #pragma unroll
            for (int j = 0; j < 8; ++j) acc[j] = fmaf(w[k], bfu2f(u[k][j]), acc[j]);
    }
    for (; e < end; e += NEP) {
        unsigned s0 = csr_src[e];
        float w0 = csr_w[e];
        u16x8 u0 = *reinterpret_cast<const u16x8*>(x + (size_t)s0 * F + sl * 8);
        #pragma unroll
        for (int j = 0; j < 8; ++j) acc[j] = fmaf(w0, bfu2f(u0[j]), acc[j]);
    }

    // combine edge slots: lanes h*LPR+sl all hold partials for slice sl
    #pragma unroll
    for (int j = 0; j < 8; ++j) {
        acc[j] += __shfl_xor(acc[j], 32);
        if constexpr (LPR == 16) acc[j] += __shfl_xor(acc[j], 16);
    }

    if (h == 0) {
        ushort hh[8];
        #pragma unroll
        for (int j = 0; j < 8; ++j) hh[j] = f2bf(acc[j]);
        *reinterpret_cast<u16x8*>(y + (size_t)node * F + sl * 8) =
            *reinterpret_cast<u16x8*>(hh);
    }
}

// ------- GEMM (PROVEN R12): bf16 A, B-in-LDS (CHT=2 -> 16KB chunks, __syncthreads),
//         64x64 wave tiles, 3-stage A pipeline, LDS-transpose epilogue, NT fp32 out

template <int NT, int SC, bool OUTB>  // K = NT*32 ; SC = N/128
__global__ __launch_bounds__(256, 4) void k_gemm7(
        const ushort* __restrict__ Ah, const ushort* __restrict__ Wt,
        const float* __restrict__ bias, void* __restrict__ Cout, int M, int N) {
    constexpr int K = NT * 32;
    constexpr int CHT = (NT > 2) ? 2 : NT;   // K-steps per staged chunk (16KB)
    constexpr int NCH = NT / CHT;            // chunks
    // union: B staging (CHT*8KB = 16KB) | epilogue transpose (4 x 16 x 68 f32 = 17.4KB)
    __shared__ __align__(16) float smem[4352];
    short* sB = (short*)smem;

    // bijective XCD swizzle
    int nwg = (int)gridDim.x;
    int bid = (int)blockIdx.x;
    int q = nwg >> 3, r = nwg & 7;
    int xcd = bid & 7, seq = bid >> 3;
    int swz = (xcd < r ? xcd * (q + 1) : r * (q + 1) + (xcd - r) * q) + seq;
    int bx = swz % SC, by = swz / SC;
    int col0 = bx * 128, row0 = by * 128;

    int tid = (int)threadIdx.x;
    int w = tid >> 6, lane = tid & 63;
    int wr = w >> 1, wc = w & 1;
    int r16 = lane & 15, kg = lane >> 4;

    size_t aoff[4];
    #pragma unroll
    for (int mi = 0; mi < 4; ++mi) {
        int row = row0 + wr * 64 + mi * 16 + r16;
        if (row >= M) row = M - 1;  // clamp reads; stores guarded
        aoff[mi] = (size_t)row * K + kg * 8;
    }

    f32x4 acc[4][4] = {};
    bf16x8 ah[3][4];  // 3-stage A pipeline (compile-time indexed: loops fully unrolled)

    #pragma unroll
    for (int mi = 0; mi < 4; ++mi)
        ah[0][mi] = *reinterpret_cast<const bf16x8*>(Ah + aoff[mi]);
    if constexpr (NT > 1) {
        #pragma unroll
        for (int mi = 0; mi < 4; ++mi)
            ah[1][mi] = *reinterpret_cast<const bf16x8*>(Ah + aoff[mi] + 32);
    }

    #pragma unroll
    for (int kc = 0; kc < NCH; ++kc) {
        if (kc) __syncthreads();  // prev chunk fully consumed before overwrite
        #pragma unroll
        for (int i = 0; i < CHT * 2; ++i) {
            int c = i * 256 + tid;                     // 0 .. CHT*512-1
            int tl = c >> 9, ckg = (c >> 7) & 3, n = c & 127;
            gload16(Wt + (size_t)(col0 + n) * K + (kc * CHT + tl) * 32 + ckg * 8,
                    sB + c * 8);
        }
        __syncthreads();

        #pragma unroll
        for (int t = 0; t < CHT; ++t) {
            const int tg = kc * CHT + t;           // compile-time
            const int cur = tg % 3;
            if (tg + 2 < NT) {
                const int nxt = (tg + 2) % 3;
                #pragma unroll
                for (int mi = 0; mi < 4; ++mi)
                    ah[nxt][mi] = *reinterpret_cast<const bf16x8*>(Ah + aoff[mi] + (tg + 2) * 32);
            }
            bf16x8 bb[4];
            #pragma unroll
            for (int ni = 0; ni < 4; ++ni)
                bb[ni] = *reinterpret_cast<const bf16x8*>(
                    sB + ((t * 4 + kg) * 128 + wc * 64 + ni * 16 + r16) * 8);
            #pragma unroll
            for (int ni = 0; ni < 4; ++ni)
                #pragma unroll
                for (int mi = 0; mi < 4; ++mi)
                    acc[mi][ni] = __builtin_amdgcn_mfma_f32_16x16x32_bf16(ah[cur][mi], bb[ni], acc[mi][ni], 0, 0, 0);
        }
    }

    // ---- per-mi LDS-transpose epilogue: full-line coalesced stores ----
    __syncthreads();  // all waves done reading sB before overwrite
    float* ep = smem + w * (16 * 68);  // per-wave private 16x68 slice
    int crow0 = (lane >> 4) * 4;
    int ccol = lane & 15;
    int rb = row0 + wr * 64;
    int cb = col0 + wc * 64;
    int rl0 = lane >> 4;
    int cl = (lane & 15) * 4;
    float4 bv = *reinterpret_cast<const float4*>(&bias[cb + cl]);
    #pragma unroll
    for (int mi = 0; mi < 4; ++mi) {
        #pragma unroll
        for (int ni = 0; ni < 4; ++ni)
            #pragma unroll
            for (int j = 0; j < 4; ++j)
                ep[(crow0 + j) * 68 + ni * 16 + ccol] = acc[mi][ni][j];
        #pragma unroll
        for (int s = 0; s < 4; ++s) {
            int rl = s * 4 + rl0;
            int row = rb + mi * 16 + rl;
            if (row < M) {
                float4 vv = *reinterpret_cast<const float4*>(ep + rl * 68 + cl);
                float4 o;
                o.x = fmaxf(vv.x + bv.x, 0.f);
                o.y = fmaxf(vv.y + bv.y, 0.f);
                o.z = fmaxf(vv.z + bv.z, 0.f);
                o.w = fmaxf(vv.w + bv.w, 0.f);
                if constexpr (OUTB) {
                    *reinterpret_cast<ushort4*>((ushort*)Cout + (size_t)row * N + cb + cl) =
                        make_ushort4(f2bf(o.x), f2bf(o.y), f2bf(o.z), f2bf(o.w));
                } else {
                    f32x4 ov = {o.x, o.y, o.z, o.w};
                    __builtin_nontemporal_store(
                        ov, reinterpret_cast<f32x4*>((float*)Cout + (size_t)row * N + cb + cl));
                }
            }
        }
    }
}

// ---------------- launch ----------------

extern "C" void kernel_launch(void* const* d_in, const int* in_sizes, int n_in,
                              void* d_out, int out_size, void* d_ws, size_t ws_size,
                              hipStream_t stream) {
    const float* v  = (const float*)d_in[0];
    const int* ei   = (const int*)d_in[1];
    const float* W1 = (const float*)d_in[2];
    const float* b1 = (const float*)d_in[3];
    const float* W2 = (const float*)d_in[4];
    const float* b2 = (const float*)d_in[5];
    const float* W3 = (const float*)d_in[6];
    const float* b3 = (const float*)d_in[7];
    float* out = (float*)d_out;

    char* ws = (char*)d_ws;
    size_t off = 0;
    auto alloc = [&](size_t bytes) {
        void* p = ws + off;
        off = (off + bytes + 255) & ~(size_t)255;
        return p;
    };
    // cnt+cursor at front; dead after k_fill -> overlaid by Wt1/Wt2 (96KB <= 400KB).
    unsigned* cnt    = (unsigned*)(ws + 0);
    unsigned* cursor = (unsigned*)(ws + (size_t)NN * 4);
    ushort* Wt1 = (ushort*)ws;               // [128][128] = 32KB
    ushort* Wt2 = Wt1 + 128 * 128;           // [256][128] = 64KB
    off = ((size_t)NN * 8 + 255) & ~(size_t)255;
    unsigned* offs    = (unsigned*)alloc((size_t)(NN + 1) * 4);
    float*    dinv    = (float*)alloc((size_t)NN * 4);
    unsigned* bsum    = (unsigned*)alloc((size_t)NB * 4);
    unsigned* boff    = (unsigned*)alloc((size_t)NB * 4);
    unsigned* csr_src = (unsigned*)alloc((size_t)NE * 4);
    float*    csr_w   = (float*)alloc((size_t)NE * 4);
    // csr_src dead after agg3 -> overlaid by Wt3 [512][256] = 256KB <= 1.6MB.
    ushort* Wt3 = (ushort*)csr_src;
    ushort* aggA = (ushort*)alloc((size_t)NN * 256 * 2);  // agg output (bf16)
    ushort* vb   = (ushort*)alloc((size_t)NN * 128 * 2);  // v cast bf16
    ushort* xb   = (ushort*)alloc((size_t)NN * 256 * 2);  // x1b/x2b activations bf16

    hipMemsetAsync(cnt, 0, (size_t)NN * 8, stream);  // cnt + cursor

    k_count<<<(NE + 255) / 256, 256, 0, stream>>>(ei, cnt);
    k_dinv<<<(NN + 255) / 256, 256, 0, stream>>>(cnt, dinv);
    k_scan1<<<NB, 1024, 0, stream>>>(cnt, offs, bsum);
    k_scan2<<<1, 64, 0, stream>>>(bsum, boff, offs);
    k_scan3<<<NB, 1024, 0, stream>>>(offs, boff);
    k_fill<<<(NE + 255) / 256, 256, 0, stream>>>(ei, offs, cursor, dinv, csr_src, csr_w);

    // casts (after k_fill: cnt/cursor region is dead)
    k_castW<<<(128 * 128 + 255) / 256, 256, 0, stream>>>(W1, Wt1, 128, 128);
    k_castW<<<(128 * 256 + 255) / 256, 256, 0, stream>>>(W2, Wt2, 128, 256);
    k_castV<<<(NN * 128 / 4 + 255) / 256, 256, 0, stream>>>(v, vb, NN * 128 / 4);

    int aggGrid = (NN + 3) / 4;
    int gr = (NN + 127) / 128;  // 391 row-tiles

    // Layer 1: agg(vb) -> aggA ; GEMM K=128,N=128 -> x1b (bf16)
    k_aggregate<2><<<aggGrid, 256, 0, stream>>>(vb, aggA, offs, csr_src, csr_w, dinv);
    k_gemm7<4, 1, true><<<gr * 1, 256, 0, stream>>>(aggA, Wt1, b1, xb, NN, 128);

    // Layer 2: agg(x1b) -> aggA ; GEMM K=128,N=256 -> x2b (bf16)
    k_aggregate<2><<<aggGrid, 256, 0, stream>>>(xb, aggA, offs, csr_src, csr_w, dinv);
    k_gemm7<4, 2, true><<<gr * 2, 256, 0, stream>>>(aggA, Wt2, b2, xb, NN, 256);

    // Layer 3: agg(x2b) -> aggA ; cast W3 (csr_src now dead) ; GEMM K=256,N=512 -> out
    k_aggregate<4><<<aggGrid, 256, 0, stream>>>(xb, aggA, offs, csr_src, csr_w, dinv);
    k_castW<<<(256 * 512 + 255) / 256, 256, 0, stream>>>(W3, Wt3, 256, 512);
    k_gemm7<8, 4, false><<<gr * 4, 256, 0, stream>>>(aggA, Wt3, b3, out, NN, 512);
}

// Round 15
// 223.835 us; speedup vs baseline: 1.6423x; 1.0411x over previous
//
#include <hip/hip_runtime.h>
#include <hip/hip_bf16.h>
#include <stdint.h>

static constexpr int NN = 50000;   // nodes
static constexpr int NE = 400000;  // edges
static constexpr int NB = (NN + 1023) / 1024;  // 49 scan blocks

// prelude block ranges
static constexpr int PB_CNT = (NE + 255) / 256;            // 1563
static constexpr int PB_CV  = (NN * 128 / 4 + 255) / 256;  // 6250
static constexpr int PB_W1  = (128 * 128 + 255) / 256;     // 64
static constexpr int PB_W2  = (128 * 256 + 255) / 256;     // 128

typedef __attribute__((ext_vector_type(8))) short bf16x8;
typedef __attribute__((ext_vector_type(8))) unsigned short u16x8;
typedef __attribute__((ext_vector_type(4))) float f32x4;

__device__ inline ushort f2bf(float f) {
    __hip_bfloat16 b = __float2bfloat16(f);
    return *reinterpret_cast<ushort*>(&b);
}
__device__ inline float bfu2f(ushort u) {
    unsigned x = (unsigned)u << 16;
    return __builtin_bit_cast(float, x);
}

__device__ __forceinline__ void gload16(const void* g, void* l) {
    __builtin_amdgcn_global_load_lds(
        (const __attribute__((address_space(1))) void*)g,
        (__attribute__((address_space(3))) void*)l, 16, 0, 0);
}

// ---------------- fused prelude: edge-count | castV | castW1 | castW2 ----------------

__global__ void k_prelude(const int* __restrict__ ei, unsigned* __restrict__ cnt,
                          const float* __restrict__ v, ushort* __restrict__ vb,
                          const float* __restrict__ W1, ushort* __restrict__ Wt1,
                          const float* __restrict__ W2, ushort* __restrict__ Wt2) {
    int b = blockIdx.x;
    int tid = (int)threadIdx.x;
    if (b < PB_CNT) {
        int e = b * 256 + tid;
        if (e < NE) atomicAdd(&cnt[ei[NE + e]], 1u);
    } else if (b < PB_CNT + PB_CV) {
        int i = (b - PB_CNT) * 256 + tid;
        if (i < NN * 128 / 4) {
            float4 f = *reinterpret_cast<const float4*>(v + (size_t)i * 4);
            *reinterpret_cast<ushort4*>(vb + (size_t)i * 4) =
                make_ushort4(f2bf(f.x), f2bf(f.y), f2bf(f.z), f2bf(f.w));
        }
    } else if (b < PB_CNT + PB_CV + PB_W1) {
        int i = (b - PB_CNT - PB_CV) * 256 + tid;  // K=128, N=128
        int k = i >> 7, n = i & 127;
        Wt1[n * 128 + k] = f2bf(W1[i]);
    } else {
        int i = (b - PB_CNT - PB_CV - PB_W1) * 256 + tid;  // K=128, N=256
        int k = i >> 8, n = i & 255;
        Wt2[n * 128 + k] = f2bf(W2[i]);
    }
}

// -------- Weight cast+transpose (layer 3): W[K][N] fp32 -> Wt [N][K] bf16 --------

__global__ void k_castW(const float* __restrict__ W, ushort* __restrict__ Wt, int K, int N) {
    int i = blockIdx.x * 256 + (int)threadIdx.x;
    if (i >= K * N) return;
    int k = i / N, n = i - k * N;
    Wt[n * K + k] = f2bf(W[i]);
}

// --- hierarchical exclusive scan (dinv fused into pass 1) ---

__global__ __launch_bounds__(1024) void k_scan1(const unsigned* __restrict__ cnt,
                                                unsigned* __restrict__ offs,
                                                unsigned* __restrict__ bsum,
                                                float* __restrict__ dinv) {
    __shared__ unsigned sh[1024];
    int i = blockIdx.x * 1024 + (int)threadIdx.x;
    unsigned v = (i < NN) ? cnt[i] : 0u;
    if (i < NN) dinv[i] = rsqrtf((float)(v + 1u));  // deg includes self-loop
    sh[threadIdx.x] = v;
    __syncthreads();
    #pragma unroll
    for (int off = 1; off < 1024; off <<= 1) {
        unsigned add = (threadIdx.x >= (unsigned)off) ? sh[threadIdx.x - off] : 0u;
        __syncthreads();
        sh[threadIdx.x] += add;
        __syncthreads();
    }
    if (i < NN) offs[i] = sh[threadIdx.x] - v;  // block-local exclusive
    if (threadIdx.x == 1023) bsum[blockIdx.x] = sh[1023];
}

__global__ void k_scan2(const unsigned* __restrict__ bsum, unsigned* __restrict__ boff,
                        unsigned* __restrict__ offs) {
    if (threadIdx.x == 0) {
        unsigned acc = 0;
        for (int b = 0; b < NB; ++b) { boff[b] = acc; acc += bsum[b]; }
        offs[NN] = acc;  // == NE
    }
}

__global__ __launch_bounds__(1024) void k_scan3(unsigned* __restrict__ offs,
                                                const unsigned* __restrict__ boff) {
    int i = blockIdx.x * 1024 + (int)threadIdx.x;
    if (i < NN) offs[i] += boff[blockIdx.x];
}

__global__ void k_fill(const int* __restrict__ ei, const unsigned* __restrict__ offs,
                       unsigned* __restrict__ cursor, const float* __restrict__ dinv,
                       unsigned* __restrict__ csr_src, float* __restrict__ csr_w) {
    int e = blockIdx.x * blockDim.x + threadIdx.x;
    if (e < NE) {
        int s = ei[e];
        int d = ei[NE + e];
        unsigned pos = offs[d] + atomicAdd(&cursor[d], 1u);
        csr_src[pos] = (unsigned)s;
        csr_w[pos] = dinv[s] * dinv[d];
    }
}

// ------- Aggregation (PROVEN R14): y = A_hat * x (bf16), 8 gathers in flight -------

template <int VEC>  // F = 64*VEC
__global__ __launch_bounds__(256) void k_aggregate(
        const ushort* __restrict__ x, ushort* __restrict__ y,
        const unsigned* __restrict__ offs, const unsigned* __restrict__ csr_src,
        const float* __restrict__ csr_w, const float* __restrict__ dinv) {
    const int F = 64 * VEC;
    constexpr int LPR = (VEC == 2) ? 16 : 32;  // lanes per row (16B/lane)
    constexpr int NEP = 64 / LPR;              // parallel edge slots: 4 or 2
    constexpr int U = 8 / NEP;                 // per-slot unroll: 2 or 4
    int node = blockIdx.x * 4 + ((int)threadIdx.x >> 6);
    int lane = (int)threadIdx.x & 63;
    if (node >= NN) return;
    int h = lane / LPR;   // edge slot
    int sl = lane % LPR;  // 16B slice within row

    float di = dinv[node];
    float sw = (h == 0) ? di * di : 0.f;  // self term counted once
    float acc[8];
    {
        u16x8 u = *reinterpret_cast<const u16x8*>(x + (size_t)node * F + sl * 8);
        #pragma unroll
        for (int j = 0; j < 8; ++j) acc[j] = sw * bfu2f(u[j]);
    }

    unsigned beg = offs[node], end = offs[node + 1];
    unsigned e = beg + h;
    for (; e + NEP * (U - 1) < end; e += NEP * U) {
        unsigned s[U]; float w[U]; u16x8 u[U];
        #pragma unroll
        for (int k = 0; k < U; ++k) { s[k] = csr_src[e + NEP * k]; w[k] = csr_w[e + NEP * k]; }
        #pragma unroll
        for (int k = 0; k < U; ++k)
            u[k] = *reinterpret_cast<const u16x8*>(x + (size_t)s[k] * F + sl * 8);
        #pragma unroll
        for (int k = 0; k < U; ++k)
            #pragma unroll
            for (int j = 0; j < 8; ++j) acc[j] = fmaf(w[k], bfu2f(u[k][j]), acc[j]);
    }
    for (; e < end; e += NEP) {
        unsigned s0 = csr_src[e];
        float w0 = csr_w[e];
        u16x8 u0 = *reinterpret_cast<const u16x8*>(x + (size_t)s0 * F + sl * 8);
        #pragma unroll
        for (int j = 0; j < 8; ++j) acc[j] = fmaf(w0, bfu2f(u0[j]), acc[j]);
    }

    #pragma unroll
    for (int j = 0; j < 8; ++j) {
        acc[j] += __shfl_xor(acc[j], 32);
        if constexpr (LPR == 16) acc[j] += __shfl_xor(acc[j], 16);
    }

    if (h == 0) {
        ushort hh[8];
        #pragma unroll
        for (int j = 0; j < 8; ++j) hh[j] = f2bf(acc[j]);
        *reinterpret_cast<u16x8*>(y + (size_t)node * F + sl * 8) =
            *reinterpret_cast<u16x8*>(hh);
    }
}

// ------- GEMM v9: proper 2-phase — stage(next chunk) BEFORE compute(cur), one
//         __syncthreads per chunk (drains loads that flew under compute; WAR-safe).
//         Double-buffered B (2x16KB), 64x64 wave tiles, 3-stage A pipeline,
//         LDS-transpose epilogue, NT fp32 stores. -------

template <int NT, int SC, bool OUTB>  // K = NT*32 ; SC = N/128
__global__ __launch_bounds__(256, 4) void k_gemm9(
        const ushort* __restrict__ Ah, const ushort* __restrict__ Wt,
        const float* __restrict__ bias, void* __restrict__ Cout, int M, int N) {
    constexpr int K = NT * 32;
    constexpr int CHT = 2;            // K-steps per chunk (16KB B)
    constexpr int NCH = NT / CHT;
    // 32KB: two 16KB B buffers; epilogue (17.4KB) overlays after final sync
    __shared__ __align__(16) float smem[8192];
    short* sB = (short*)smem;

    // bijective XCD swizzle
    int nwg = (int)gridDim.x;
    int bid = (int)blockIdx.x;
    int q = nwg >> 3, r = nwg & 7;
    int xcd = bid & 7, seq = bid >> 3;
    int swz = (xcd < r ? xcd * (q + 1) : r * (q + 1) + (xcd - r) * q) + seq;
    int bx = swz % SC, by = swz / SC;
    int col0 = bx * 128, row0 = by * 128;

    int tid = (int)threadIdx.x;
    int w = tid >> 6, lane = tid & 63;
    int wr = w >> 1, wc = w & 1;
    int r16 = lane & 15, kg = lane >> 4;

    size_t aoff[4];
    #pragma unroll
    for (int mi = 0; mi < 4; ++mi) {
        int row = row0 + wr * 64 + mi * 16 + r16;
        if (row >= M) row = M - 1;  // clamp reads; stores guarded
        aoff[mi] = (size_t)row * K + kg * 8;
    }

    auto stage = [&](int b, int kc) {
        short* dst = sB + b * 8192;  // 8192 shorts = 16KB
        #pragma unroll
        for (int i = 0; i < CHT * 2; ++i) {
            int c = i * 256 + tid;
            int tl = c >> 9, ckg = (c >> 7) & 3, n = c & 127;
            gload16(Wt + (size_t)(col0 + n) * K + (kc * CHT + tl) * 32 + ckg * 8,
                    dst + c * 8);
        }
    };

    f32x4 acc[4][4] = {};
    bf16x8 ah[3][4];  // 3-stage A pipeline (compile-time indexed: loops fully unrolled)

    #pragma unroll
    for (int mi = 0; mi < 4; ++mi)
        ah[0][mi] = *reinterpret_cast<const bf16x8*>(Ah + aoff[mi]);
    #pragma unroll
    for (int mi = 0; mi < 4; ++mi)
        ah[1][mi] = *reinterpret_cast<const bf16x8*>(Ah + aoff[mi] + 32);

    stage(0, 0);
    __syncthreads();

    #pragma unroll
    for (int kc = 0; kc < NCH; ++kc) {
        if (kc + 1 < NCH) stage((kc + 1) & 1, kc + 1);  // flies under this chunk's compute
        const short* sb = sB + (kc & 1) * 8192;
        #pragma unroll
        for (int t = 0; t < CHT; ++t) {
            const int tg = kc * CHT + t;  // compile-time under full unroll
            const int cur = tg % 3;
            if (tg + 2 < NT) {
                const int nxt = (tg + 2) % 3;
                #pragma unroll
                for (int mi = 0; mi < 4; ++mi)
                    ah[nxt][mi] = *reinterpret_cast<const bf16x8*>(Ah + aoff[mi] + (tg + 2) * 32);
            }
            bf16x8 bb[4];
            #pragma unroll
            for (int ni = 0; ni < 4; ++ni)
                bb[ni] = *reinterpret_cast<const bf16x8*>(
                    sb + ((t * 4 + kg) * 128 + wc * 64 + ni * 16 + r16) * 8);
            #pragma unroll
            for (int ni = 0; ni < 4; ++ni)
                #pragma unroll
                for (int mi = 0; mi < 4; ++mi)
                    acc[mi][ni] = __builtin_amdgcn_mfma_f32_16x16x32_bf16(ah[cur][mi], bb[ni], acc[mi][ni], 0, 0, 0);
        }
        __syncthreads();  // next-stage loads landed during compute; WAR-safe buffer swap
    }

    // ---- per-mi LDS-transpose epilogue (loop's final sync guards the overlay) ----
    float* ep = smem + w * (16 * 68);  // per-wave private 16x68 slice
    int crow0 = (lane >> 4) * 4;
    int ccol = lane & 15;
    int rb = row0 + wr * 64;
    int cb = col0 + wc * 64;
    int rl0 = lane >> 4;
    int cl = (lane & 15) * 4;
    float4 bv = *reinterpret_cast<const float4*>(&bias[cb + cl]);
    #pragma unroll
    for (int mi = 0; mi < 4; ++mi) {
        #pragma unroll
        for (int ni = 0; ni < 4; ++ni)
            #pragma unroll
            for (int j = 0; j < 4; ++j)
                ep[(crow0 + j) * 68 + ni * 16 + ccol] = acc[mi][ni][j];
        #pragma unroll
        for (int s = 0; s < 4; ++s) {
            int rl = s * 4 + rl0;
            int row = rb + mi * 16 + rl;
            if (row < M) {
                float4 vv = *reinterpret_cast<const float4*>(ep + rl * 68 + cl);
                float4 o;
                o.x = fmaxf(vv.x + bv.x, 0.f);
                o.y = fmaxf(vv.y + bv.y, 0.f);
                o.z = fmaxf(vv.z + bv.z, 0.f);
                o.w = fmaxf(vv.w + bv.w, 0.f);
                if constexpr (OUTB) {
                    *reinterpret_cast<ushort4*>((ushort*)Cout + (size_t)row * N + cb + cl) =
                        make_ushort4(f2bf(o.x), f2bf(o.y), f2bf(o.z), f2bf(o.w));
                } else {
                    f32x4 ov = {o.x, o.y, o.z, o.w};
                    __builtin_nontemporal_store(
                        ov, reinterpret_cast<f32x4*>((float*)Cout + (size_t)row * N + cb + cl));
                }
            }
        }
    }
}

// ---------------- launch ----------------

extern "C" void kernel_launch(void* const* d_in, const int* in_sizes, int n_in,
                              void* d_out, int out_size, void* d_ws, size_t ws_size,
                              hipStream_t stream) {
    const float* v  = (const float*)d_in[0];
    const int* ei   = (const int*)d_in[1];
    const float* W1 = (const float*)d_in[2];
    const float* b1 = (const float*)d_in[3];
    const float* W2 = (const float*)d_in[4];
    const float* b2 = (const float*)d_in[5];
    const float* W3 = (const float*)d_in[6];
    const float* b3 = (const float*)d_in[7];
    float* out = (float*)d_out;

    char* ws = (char*)d_ws;
    size_t off = 0;
    auto alloc = [&](size_t bytes) {
        void* p = ws + off;
        off = (off + bytes + 255) & ~(size_t)255;
        return p;
    };
    // cnt+cursor at front (memset together). Wt1/Wt2 now have dedicated storage
    // (prelude writes them concurrently with count).
    unsigned* cnt    = (unsigned*)(ws + 0);
    unsigned* cursor = (unsigned*)(ws + (size_t)NN * 4);
    off = ((size_t)NN * 8 + 255) & ~(size_t)255;
    ushort* Wt1 = (ushort*)alloc(128 * 128 * 2);   // 32KB
    ushort* Wt2 = (ushort*)alloc(128 * 256 * 2);   // 64KB
    unsigned* offs    = (unsigned*)alloc((size_t)(NN + 1) * 4);
    float*    dinv    = (float*)alloc((size_t)NN * 4);
    unsigned* bsum    = (unsigned*)alloc((size_t)NB * 4);
    unsigned* boff    = (unsigned*)alloc((size_t)NB * 4);
    unsigned* csr_src = (unsigned*)alloc((size_t)NE * 4);
    float*    csr_w   = (float*)alloc((size_t)NE * 4);
    // csr_src dead after agg3 -> overlaid by Wt3 [512][256] = 256KB <= 1.6MB.
    ushort* Wt3 = (ushort*)csr_src;
    ushort* aggA = (ushort*)alloc((size_t)NN * 256 * 2);  // agg output (bf16)
    ushort* vb   = (ushort*)alloc((size_t)NN * 128 * 2);  // v cast bf16
    ushort* xb   = (ushort*)alloc((size_t)NN * 256 * 2);  // x1b/x2b activations bf16

    hipMemsetAsync(cnt, 0, (size_t)NN * 8, stream);  // cnt + cursor

    // fused prelude: count | castV | castW1 | castW2
    k_prelude<<<PB_CNT + PB_CV + PB_W1 + PB_W2, 256, 0, stream>>>(
        ei, cnt, v, vb, W1, Wt1, W2, Wt2);
    k_scan1<<<NB, 1024, 0, stream>>>(cnt, offs, bsum, dinv);
    k_scan2<<<1, 64, 0, stream>>>(bsum, boff, offs);
    k_scan3<<<NB, 1024, 0, stream>>>(offs, boff);
    k_fill<<<(NE + 255) / 256, 256, 0, stream>>>(ei, offs, cursor, dinv, csr_src, csr_w);

    int aggGrid = (NN + 3) / 4;
    int gr = (NN + 127) / 128;  // 391 row-tiles

    // Layer 1: agg(vb) -> aggA ; GEMM K=128,N=128 -> x1b (bf16)
    k_aggregate<2><<<aggGrid, 256, 0, stream>>>(vb, aggA, offs, csr_src, csr_w, dinv);
    k_gemm9<4, 1, true><<<gr * 1, 256, 0, stream>>>(aggA, Wt1, b1, xb, NN, 128);

    // Layer 2: agg(x1b) -> aggA ; GEMM K=128,N=256 -> x2b (bf16)
    k_aggregate<2><<<aggGrid, 256, 0, stream>>>(xb, aggA, offs, csr_src, csr_w, dinv);
    k_gemm9<4, 2, true><<<gr * 2, 256, 0, stream>>>(aggA, Wt2, b2, xb, NN, 256);

    // Layer 3: agg(x2b) -> aggA ; cast W3 (csr_src now dead) ; GEMM K=256,N=512 -> out
    k_aggregate<4><<<aggGrid, 256, 0, stream>>>(xb, aggA, offs, csr_src, csr_w, dinv);
    k_castW<<<(256 * 512 + 255) / 256, 256, 0, stream>>>(W3, Wt3, 256, 512);
    k_gemm9<8, 4, false><<<gr * 4, 256, 0, stream>>>(aggA, Wt3, b3, out, NN, 512);
}

// Round 16
// 220.729 us; speedup vs baseline: 1.6654x; 1.0141x over previous
//
#include <hip/hip_runtime.h>
#include <hip/hip_bf16.h>
#include <stdint.h>

static constexpr int NN = 50000;   // nodes
static constexpr int NE = 400000;  // edges
static constexpr int NB = (NN + 1023) / 1024;  // 49 scan blocks

// prelude block ranges
static constexpr int PB_CNT = (NE + 255) / 256;            // 1563
static constexpr int PB_CV  = (NN * 128 / 4 + 255) / 256;  // 6250
static constexpr int PB_W1  = (128 * 128) / 256;           // 64
static constexpr int PB_W2  = (128 * 256) / 256;           // 128
static constexpr int PB_W3  = (256 * 512) / 256;           // 512

typedef __attribute__((ext_vector_type(8))) short bf16x8;
typedef __attribute__((ext_vector_type(8))) unsigned short u16x8;
typedef __attribute__((ext_vector_type(4))) float f32x4;

__device__ inline ushort f2bf(float f) {
    __hip_bfloat16 b = __float2bfloat16(f);
    return *reinterpret_cast<ushort*>(&b);
}
__device__ inline float bfu2f(ushort u) {
    unsigned x = (unsigned)u << 16;
    return __builtin_bit_cast(float, x);
}

__device__ __forceinline__ void gload16(const void* g, void* l) {
    __builtin_amdgcn_global_load_lds(
        (const __attribute__((address_space(1))) void*)g,
        (__attribute__((address_space(3))) void*)l, 16, 0, 0);
}

// ------- fused prelude: count | castV | castW1 | castW2 | castW3 -------

__global__ void k_prelude(const int* __restrict__ ei, unsigned* __restrict__ cnt,
                          const float* __restrict__ v, ushort* __restrict__ vb,
                          const float* __restrict__ W1, ushort* __restrict__ Wt1,
                          const float* __restrict__ W2, ushort* __restrict__ Wt2,
                          const float* __restrict__ W3, ushort* __restrict__ Wt3) {
    int b = blockIdx.x;
    int tid = (int)threadIdx.x;
    if (b < PB_CNT) {
        int e = b * 256 + tid;
        if (e < NE) atomicAdd(&cnt[ei[NE + e]], 1u);
    } else if (b < PB_CNT + PB_CV) {
        int i = (b - PB_CNT) * 256 + tid;
        if (i < NN * 128 / 4) {
            float4 f = *reinterpret_cast<const float4*>(v + (size_t)i * 4);
            *reinterpret_cast<ushort4*>(vb + (size_t)i * 4) =
                make_ushort4(f2bf(f.x), f2bf(f.y), f2bf(f.z), f2bf(f.w));
        }
    } else if (b < PB_CNT + PB_CV + PB_W1) {
        int i = (b - PB_CNT - PB_CV) * 256 + tid;  // K=128, N=128
        int k = i >> 7, n = i & 127;
        Wt1[n * 128 + k] = f2bf(W1[i]);
    } else if (b < PB_CNT + PB_CV + PB_W1 + PB_W2) {
        int i = (b - PB_CNT - PB_CV - PB_W1) * 256 + tid;  // K=128, N=256
        int k = i >> 8, n = i & 255;
        Wt2[n * 128 + k] = f2bf(W2[i]);
    } else {
        int i = (b - PB_CNT - PB_CV - PB_W1 - PB_W2) * 256 + tid;  // K=256, N=512
        int k = i >> 9, n = i & 511;
        Wt3[n * 256 + k] = f2bf(W3[i]);
    }
}

// --- hierarchical exclusive scan (dinv fused into pass 1; passes 2+3 fused) ---

__global__ __launch_bounds__(1024) void k_scan1(const unsigned* __restrict__ cnt,
                                                unsigned* __restrict__ offs,
                                                unsigned* __restrict__ bsum,
                                                float* __restrict__ dinv) {
    __shared__ unsigned sh[1024];
    int i = blockIdx.x * 1024 + (int)threadIdx.x;
    unsigned v = (i < NN) ? cnt[i] : 0u;
    if (i < NN) dinv[i] = rsqrtf((float)(v + 1u));  // deg includes self-loop
    sh[threadIdx.x] = v;
    __syncthreads();
    #pragma unroll
    for (int off = 1; off < 1024; off <<= 1) {
        unsigned add = (threadIdx.x >= (unsigned)off) ? sh[threadIdx.x - off] : 0u;
        __syncthreads();
        sh[threadIdx.x] += add;
        __syncthreads();
    }
    if (i < NN) offs[i] = sh[threadIdx.x] - v;  // block-local exclusive
    if (threadIdx.x == 1023) bsum[blockIdx.x] = sh[1023];
}

// fused scan2+scan3: each block computes its own prefix of bsum inline and adds.
__global__ __launch_bounds__(1024) void k_scan23(unsigned* __restrict__ offs,
                                                 const unsigned* __restrict__ bsum) {
    int b = blockIdx.x;
    unsigned boff = 0;
    for (int j = 0; j < b; ++j) boff += bsum[j];  // <=48 L2 reads
    int i = b * 1024 + (int)threadIdx.x;
    if (i < NN) offs[i] += boff;
    if (b == 0 && threadIdx.x == 0) offs[NN] = NE;  // total is always NE
}

__global__ void k_fill(const int* __restrict__ ei, const unsigned* __restrict__ offs,
                       unsigned* __restrict__ cursor, const float* __restrict__ dinv,
                       unsigned* __restrict__ csr_src, float* __restrict__ csr_w) {
    int e = blockIdx.x * blockDim.x + threadIdx.x;
    if (e < NE) {
        int s = ei[e];
        int d = ei[NE + e];
        unsigned pos = offs[d] + atomicAdd(&cursor[d], 1u);
        csr_src[pos] = (unsigned)s;
        csr_w[pos] = dinv[s] * dinv[d];
    }
}

// ------- Aggregation (PROVEN R14): y = A_hat * x (bf16), 8 gathers in flight -------

template <int VEC>  // F = 64*VEC
__global__ __launch_bounds__(256) void k_aggregate(
        const ushort* __restrict__ x, ushort* __restrict__ y,
        const unsigned* __restrict__ offs, const unsigned* __restrict__ csr_src,
        const float* __restrict__ csr_w, const float* __restrict__ dinv) {
    const int F = 64 * VEC;
    constexpr int LPR = (VEC == 2) ? 16 : 32;  // lanes per row (16B/lane)
    constexpr int NEP = 64 / LPR;              // parallel edge slots: 4 or 2
    constexpr int U = 8 / NEP;                 // per-slot unroll: 2 or 4
    int node = blockIdx.x * 4 + ((int)threadIdx.x >> 6);
    int lane = (int)threadIdx.x & 63;
    if (node >= NN) return;
    int h = lane / LPR;   // edge slot
    int sl = lane % LPR;  // 16B slice within row

    float di = dinv[node];
    float sw = (h == 0) ? di * di : 0.f;  // self term counted once
    float acc[8];
    {
        u16x8 u = *reinterpret_cast<const u16x8*>(x + (size_t)node * F + sl * 8);
        #pragma unroll
        for (int j = 0; j < 8; ++j) acc[j] = sw * bfu2f(u[j]);
    }

    unsigned beg = offs[node], end = offs[node + 1];
    unsigned e = beg + h;
    for (; e + NEP * (U - 1) < end; e += NEP * U) {
        unsigned s[U]; float w[U]; u16x8 u[U];
        #pragma unroll
        for (int k = 0; k < U; ++k) { s[k] = csr_src[e + NEP * k]; w[k] = csr_w[e + NEP * k]; }
        #pragma unroll
        for (int k = 0; k < U; ++k)
            u[k] = *reinterpret_cast<const u16x8*>(x + (size_t)s[k] * F + sl * 8);
        #pragma unroll
        for (int k = 0; k < U; ++k)
            #pragma unroll
            for (int j = 0; j < 8; ++j) acc[j] = fmaf(w[k], bfu2f(u[k][j]), acc[j]);
    }
    for (; e < end; e += NEP) {
        unsigned s0 = csr_src[e];
        float w0 = csr_w[e];
        u16x8 u0 = *reinterpret_cast<const u16x8*>(x + (size_t)s0 * F + sl * 8);
        #pragma unroll
        for (int j = 0; j < 8; ++j) acc[j] = fmaf(w0, bfu2f(u0[j]), acc[j]);
    }

    #pragma unroll
    for (int j = 0; j < 8; ++j) {
        acc[j] += __shfl_xor(acc[j], 32);
        if constexpr (LPR == 16) acc[j] += __shfl_xor(acc[j], 16);
    }

    if (h == 0) {
        ushort hh[8];
        #pragma unroll
        for (int j = 0; j < 8; ++j) hh[j] = f2bf(acc[j]);
        *reinterpret_cast<u16x8*>(y + (size_t)node * F + sl * 8) =
            *reinterpret_cast<u16x8*>(hh);
    }
}

// ------- GEMM v9 (PROVEN R15): 2-phase stage-before-compute, double-buffered B,
//         64x64 wave tiles, 3-stage A pipeline, LDS-transpose epilogue, NT fp32 out

template <int NT, int SC, bool OUTB>  // K = NT*32 ; SC = N/128
__global__ __launch_bounds__(256, 4) void k_gemm9(
        const ushort* __restrict__ Ah, const ushort* __restrict__ Wt,
        const float* __restrict__ bias, void* __restrict__ Cout, int M, int N) {
    constexpr int K = NT * 32;
    constexpr int CHT = 2;            // K-steps per chunk (16KB B)
    constexpr int NCH = NT / CHT;
    // 32KB: two 16KB B buffers; epilogue (17.4KB) overlays after final sync
    __shared__ __align__(16) float smem[8192];
    short* sB = (short*)smem;

    // bijective XCD swizzle
    int nwg = (int)gridDim.x;
    int bid = (int)blockIdx.x;
    int q = nwg >> 3, r = nwg & 7;
    int xcd = bid & 7, seq = bid >> 3;
    int swz = (xcd < r ? xcd * (q + 1) : r * (q + 1) + (xcd - r) * q) + seq;
    int bx = swz % SC, by = swz / SC;
    int col0 = bx * 128, row0 = by * 128;

    int tid = (int)threadIdx.x;
    int w = tid >> 6, lane = tid & 63;
    int wr = w >> 1, wc = w & 1;
    int r16 = lane & 15, kg = lane >> 4;

    size_t aoff[4];
    #pragma unroll
    for (int mi = 0; mi < 4; ++mi) {
        int row = row0 + wr * 64 + mi * 16 + r16;
        if (row >= M) row = M - 1;  // clamp reads; stores guarded
        aoff[mi] = (size_t)row * K + kg * 8;
    }

    auto stage = [&](int b, int kc) {
        short* dst = sB + b * 8192;  // 8192 shorts = 16KB
        #pragma unroll
        for (int i = 0; i < CHT * 2; ++i) {
            int c = i * 256 + tid;
            int tl = c >> 9, ckg = (c >> 7) & 3, n = c & 127;
            gload16(Wt + (size_t)(col0 + n) * K + (kc * CHT + tl) * 32 + ckg * 8,
                    dst + c * 8);
        }
    };

    f32x4 acc[4][4] = {};
    bf16x8 ah[3][4];  // 3-stage A pipeline (compile-time indexed: loops fully unrolled)

    #pragma unroll
    for (int mi = 0; mi < 4; ++mi)
        ah[0][mi] = *reinterpret_cast<const bf16x8*>(Ah + aoff[mi]);
    #pragma unroll
    for (int mi = 0; mi < 4; ++mi)
        ah[1][mi] = *reinterpret_cast<const bf16x8*>(Ah + aoff[mi] + 32);

    stage(0, 0);
    __syncthreads();

    #pragma unroll
    for (int kc = 0; kc < NCH; ++kc) {
        if (kc + 1 < NCH) stage((kc + 1) & 1, kc + 1);  // flies under this chunk's compute
        const short* sb = sB + (kc & 1) * 8192;
        #pragma unroll
        for (int t = 0; t < CHT; ++t) {
            const int tg = kc * CHT + t;  // compile-time under full unroll
            const int cur = tg % 3;
            if (tg + 2 < NT) {
                const int nxt = (tg + 2) % 3;
                #pragma unroll
                for (int mi = 0; mi < 4; ++mi)
                    ah[nxt][mi] = *reinterpret_cast<const bf16x8*>(Ah + aoff[mi] + (tg + 2) * 32);
            }
            bf16x8 bb[4];
            #pragma unroll
            for (int ni = 0; ni < 4; ++ni)
                bb[ni] = *reinterpret_cast<const bf16x8*>(
                    sb + ((t * 4 + kg) * 128 + wc * 64 + ni * 16 + r16) * 8);
            #pragma unroll
            for (int ni = 0; ni < 4; ++ni)
                #pragma unroll
                for (int mi = 0; mi < 4; ++mi)
                    acc[mi][ni] = __builtin_amdgcn_mfma_f32_16x16x32_bf16(ah[cur][mi], bb[ni], acc[mi][ni], 0, 0, 0);
        }
        __syncthreads();  // next-stage loads landed during compute; WAR-safe buffer swap
    }

    // ---- per-mi LDS-transpose epilogue (loop's final sync guards the overlay) ----
    float* ep = smem + w * (16 * 68);  // per-wave private 16x68 slice
    int crow0 = (lane >> 4) * 4;
    int ccol = lane & 15;
    int rb = row0 + wr * 64;
    int cb = col0 + wc * 64;
    int rl0 = lane >> 4;
    int cl = (lane & 15) * 4;
    float4 bv = *reinterpret_cast<const float4*>(&bias[cb + cl]);
    #pragma unroll
    for (int mi = 0; mi < 4; ++mi) {
        #pragma unroll
        for (int ni = 0; ni < 4; ++ni)
            #pragma unroll
            for (int j = 0; j < 4; ++j)
                ep[(crow0 + j) * 68 + ni * 16 + ccol] = acc[mi][ni][j];
        #pragma unroll
        for (int s = 0; s < 4; ++s) {
            int rl = s * 4 + rl0;
            int row = rb + mi * 16 + rl;
            if (row < M) {
                float4 vv = *reinterpret_cast<const float4*>(ep + rl * 68 + cl);
                float4 o;
                o.x = fmaxf(vv.x + bv.x, 0.f);
                o.y = fmaxf(vv.y + bv.y, 0.f);
                o.z = fmaxf(vv.z + bv.z, 0.f);
                o.w = fmaxf(vv.w + bv.w, 0.f);
                if constexpr (OUTB) {
                    *reinterpret_cast<ushort4*>((ushort*)Cout + (size_t)row * N + cb + cl) =
                        make_ushort4(f2bf(o.x), f2bf(o.y), f2bf(o.z), f2bf(o.w));
                } else {
                    f32x4 ov = {o.x, o.y, o.z, o.w};
                    __builtin_nontemporal_store(
                        ov, reinterpret_cast<f32x4*>((float*)Cout + (size_t)row * N + cb + cl));
                }
            }
        }
    }
}

// ---------------- launch ----------------

extern "C" void kernel_launch(void* const* d_in, const int* in_sizes, int n_in,
                              void* d_out, int out_size, void* d_ws, size_t ws_size,
                              hipStream_t stream) {
    const float* v  = (const float*)d_in[0];
    const int* ei   = (const int*)d_in[1];
    const float* W1 = (const float*)d_in[2];
    const float* b1 = (const float*)d_in[3];
    const float* W2 = (const float*)d_in[4];
    const float* b2 = (const float*)d_in[5];
    const float* W3 = (const float*)d_in[6];
    const float* b3 = (const float*)d_in[7];
    float* out = (float*)d_out;

    char* ws = (char*)d_ws;
    size_t off = 0;
    auto alloc = [&](size_t bytes) {
        void* p = ws + off;
        off = (off + bytes + 255) & ~(size_t)255;
        return p;
    };
    // cnt+cursor at front (memset together).
    unsigned* cnt    = (unsigned*)(ws + 0);
    unsigned* cursor = (unsigned*)(ws + (size_t)NN * 4);
    off = ((size_t)NN * 8 + 255) & ~(size_t)255;
    ushort* Wt1 = (ushort*)alloc(128 * 128 * 2);   // 32KB
    ushort* Wt2 = (ushort*)alloc(128 * 256 * 2);   // 64KB
    ushort* Wt3 = (ushort*)alloc(256 * 512 * 2);   // 256KB (dedicated; prelude-written)
    unsigned* offs    = (unsigned*)alloc((size_t)(NN + 1) * 4);
    float*    dinv    = (float*)alloc((size_t)NN * 4);
    unsigned* bsum    = (unsigned*)alloc((size_t)NB * 4);
    unsigned* csr_src = (unsigned*)alloc((size_t)NE * 4);
    float*    csr_w   = (float*)alloc((size_t)NE * 4);
    ushort* aggA = (ushort*)alloc((size_t)NN * 256 * 2);  // agg output (bf16)
    ushort* vb   = (ushort*)alloc((size_t)NN * 128 * 2);  // v cast bf16
    ushort* xb   = (ushort*)alloc((size_t)NN * 256 * 2);  // x1b/x2b activations bf16

    hipMemsetAsync(cnt, 0, (size_t)NN * 8, stream);  // cnt + cursor

    // fused prelude: count | castV | castW1 | castW2 | castW3
    k_prelude<<<PB_CNT + PB_CV + PB_W1 + PB_W2 + PB_W3, 256, 0, stream>>>(
        ei, cnt, v, vb, W1, Wt1, W2, Wt2, W3, Wt3);
    k_scan1<<<NB, 1024, 0, stream>>>(cnt, offs, bsum, dinv);
    k_scan23<<<NB, 1024, 0, stream>>>(offs, bsum);
    k_fill<<<(NE + 255) / 256, 256, 0, stream>>>(ei, offs, cursor, dinv, csr_src, csr_w);

    int aggGrid = (NN + 3) / 4;
    int gr = (NN + 127) / 128;  // 391 row-tiles

    // Layer 1: agg(vb) -> aggA ; GEMM K=128,N=128 -> x1b (bf16)
    k_aggregate<2><<<aggGrid, 256, 0, stream>>>(vb, aggA, offs, csr_src, csr_w, dinv);
    k_gemm9<4, 1, true><<<gr * 1, 256, 0, stream>>>(aggA, Wt1, b1, xb, NN, 128);

    // Layer 2: agg(x1b) -> aggA ; GEMM K=128,N=256 -> x2b (bf16)
    k_aggregate<2><<<aggGrid, 256, 0, stream>>>(xb, aggA, offs, csr_src, csr_w, dinv);
    k_gemm9<4, 2, true><<<gr * 2, 256, 0, stream>>>(aggA, Wt2, b2, xb, NN, 256);

    // Layer 3: agg(x2b) -> aggA ; GEMM K=256,N=512 -> out (fp32)
    k_aggregate<4><<<aggGrid, 256, 0, stream>>>(xb, aggA, offs, csr_src, csr_w, dinv);
    k_gemm9<8, 4, false><<<gr * 4, 256, 0, stream>>>(aggA, Wt3, b3, out, NN, 512);
}